// Round 10
// baseline (496.903 us; speedup 1.0000x reference)
//
#include <hip/hip_runtime.h>
#include <math.h>

#define NN 50000
#define NE 800000
#define NRT 782          // row tiles of 64
#define NT  (NRT * 2)    // x2 col-halves = 1564 blocks per GEMM
#define SCB 256          // scatter blocks (block-owned dst ranges)
#define NPB 196          // nodes per scatter block (256*196 >= 50000)

typedef __attribute__((ext_vector_type(8))) short short8;
typedef __attribute__((ext_vector_type(4))) float floatx4;

#define AS1 __attribute__((address_space(1)))
#define AS3 __attribute__((address_space(3)))

__device__ __forceinline__ unsigned short f2bf(float f) {
    unsigned u = __float_as_uint(f);
    unsigned r = (u + 0x7fff + ((u >> 16) & 1)) >> 16;
    return (unsigned short)r;
}
__device__ __forceinline__ float bf2f(unsigned short h) {
    return __uint_as_float(((unsigned)h) << 16);
}

// ---------------- CSR scans ----------------

__global__ void k_scan_part(const int* __restrict__ deg, int* __restrict__ partials) {
    __shared__ int s[1024];
    int idx = blockIdx.x * 1024 + threadIdx.x;
    s[threadIdx.x] = (idx < NN) ? deg[idx] : 0;
    for (int off = 512; off > 0; off >>= 1) {
        __syncthreads();
        if (threadIdx.x < off) s[threadIdx.x] += s[threadIdx.x + off];
    }
    if (threadIdx.x == 0) partials[blockIdx.x] = s[0];
}

__global__ void k_scan_top(int* __restrict__ partials, int* __restrict__ row_start, int n) {
    int lane = threadIdx.x;
    int orig = (lane < n) ? partials[lane] : 0;
    int v = orig;
    for (int off = 1; off < 64; off <<= 1) {
        int u = __shfl_up(v, off, 64);
        if (lane >= off) v += u;
    }
    if (lane < n) partials[lane] = v - orig;   // exclusive
    if (lane == 63) row_start[NN] = v;
}

__global__ void k_scan_final(const int* __restrict__ deg, const int* __restrict__ partials,
                             int* __restrict__ row_start) {
    __shared__ int s[1024];
    int idx = blockIdx.x * 1024 + threadIdx.x;
    int v = (idx < NN) ? deg[idx] : 0;
    s[threadIdx.x] = v;
    for (int off = 1; off < 1024; off <<= 1) {
        __syncthreads();
        int tmp = (threadIdx.x >= off) ? s[threadIdx.x - off] : 0;
        __syncthreads();
        s[threadIdx.x] += tmp;
    }
    if (idx < NN) row_start[idx] = partials[blockIdx.x] + s[threadIdx.x] - v;
}

// ---------------- prep: cvt (h->bf16) | hist | packW ----------------

__global__ __launch_bounds__(256)
void k_prep(const float* __restrict__ h, unsigned short* __restrict__ hB,
            const int* __restrict__ dst, int* __restrict__ deg,
            const float* w0, const float* w1, const float* w2, const float* w3,
            const float* w4, const float* w5, const float* w6, const float* w7,
            short* __restrict__ wpk) {
    int bid = blockIdx.x;
    if (bid < 3125) {              // cvt
        int i = (bid * 256 + threadIdx.x) * 8;
        float4 a = *(const float4*)&h[i];
        float4 b = *(const float4*)&h[i + 4];
        short8 v;
        v[0] = (short)f2bf(a.x); v[1] = (short)f2bf(a.y);
        v[2] = (short)f2bf(a.z); v[3] = (short)f2bf(a.w);
        v[4] = (short)f2bf(b.x); v[5] = (short)f2bf(b.y);
        v[6] = (short)f2bf(b.z); v[7] = (short)f2bf(b.w);
        *(short8*)&hB[i] = v;
    } else if (bid < 6250) {       // hist
        int e = (bid - 3125) * 256 + threadIdx.x;
        if (e < NE) atomicAdd(&deg[dst[e]], 1);
    } else {                       // packW, 8 blocks
        int wb = bid - 6250;
        const float* W;
        switch (wb) {
            case 0: W = w0; break; case 1: W = w1; break;
            case 2: W = w2; break; case 3: W = w3; break;
            case 4: W = w4; break; case 5: W = w5; break;
            case 6: W = w6; break; default: W = w7; break;
        }
        short* dstp = wpk + (size_t)wb * 16384;
#pragma unroll
        for (int i = 0; i < 8; ++i) {
            int q = threadIdx.x + i * 256;
            int cb = q >> 8, ks = (q >> 6) & 3, lane = q & 63;
            int n = lane & 15, g = lane >> 4;
            int col = cb * 16 + n, krow = ks * 32 + g * 8;
            short8 v;
#pragma unroll
            for (int j = 0; j < 8; ++j)
                v[j] = (short)f2bf(W[(krow + j) * 128 + col]);
            *(short8*)&dstp[q * 8] = v;
        }
    }
}

// ---------------- GEMM body: 64x64 tile, 4 waves, wave = 16 rows ----------------

template<int DUAL, int DOELU, int OUTF32, int NOBIAS, int BIAS2>
__device__ __forceinline__ void gemm_body(
        int bid,
        const unsigned short* __restrict__ A, const unsigned short* __restrict__ A2,
        const short* __restrict__ Wp, const short* __restrict__ Wp2,
        const float* __restrict__ bias, const float* __restrict__ bias2,
        void* outv, short* sW, short* sA) {
    const int t = threadIdx.x;
    const int wv = t >> 6, lane = t & 63;
    const int rb = bid >> 1, ct = bid & 1;
    const int row0 = rb * 64, col0 = ct * 64;
    const int m = lane & 15, g = lane >> 4;

    floatx4 acc[4];
#pragma unroll
    for (int cb = 0; cb < 4; ++cb) acc[cb] = (floatx4){0.f, 0.f, 0.f, 0.f};

    const int npass = DUAL ? 2 : 1;
    for (int pass = 0; pass < npass; ++pass) {
        const unsigned short* Ac = pass ? A2 : A;
        const short* Wc = (pass ? Wp2 : Wp) + ct * 8192;   // col-half of packed W
        __syncthreads();
#pragma unroll
        for (int i = 0; i < 4; ++i) {   // stage W: 1024 x 16B linear
            int cbase = (i * 4 + wv) * 64;
            __builtin_amdgcn_global_load_lds(
                (const AS1 unsigned int*)(Wc + (size_t)(cbase + lane) * 8),
                (AS3 unsigned int*)(sW + cbase * 8), 16, 0, 0);
        }
#pragma unroll
        for (int i = 0; i < 4; ++i) {   // stage A: swizzled source
            int cbase = (i * 4 + wv) * 64;
            int id = cbase + lane;
            int r = id >> 4, cs = id & 15;
            int rg = row0 + r; if (rg >= NN) rg = NN - 1;
            int csrc = cs ^ (r & 7);
            __builtin_amdgcn_global_load_lds(
                (const AS1 unsigned int*)(Ac + (size_t)rg * 128 + csrc * 8),
                (AS3 unsigned int*)(sA + cbase * 8), 16, 0, 0);
        }
        asm volatile("s_waitcnt vmcnt(0)" ::: "memory");
        __builtin_amdgcn_sched_barrier(0);
        __syncthreads();

        const int r0 = wv * 16;
#pragma unroll
        for (int ks = 0; ks < 4; ++ks) {
            int cxor = (ks * 4 + g) ^ (m & 7);
            short8 af = *(const short8*)&sA[((r0 + m) * 16 + cxor) * 8];
#pragma unroll
            for (int cb = 0; cb < 4; ++cb) {
                short8 bf = *(const short8*)&sW[((cb * 4 + ks) * 64 + lane) * 8];
                acc[cb] = __builtin_amdgcn_mfma_f32_16x16x32_bf16(af, bf, acc[cb], 0, 0, 0);
            }
        }
    }

    // epilogue: C/D layout col=lane&15, row=(lane>>4)*4+reg
    const int rowbase = row0 + wv * 16 + g * 4;
#pragma unroll
    for (int cb = 0; cb < 4; ++cb) {
        int C = col0 + cb * 16 + m;
        float bb = NOBIAS ? 0.f : bias[C];
        if (BIAS2) bb += bias2[C];
#pragma unroll
        for (int rr = 0; rr < 4; ++rr) {
            int R = rowbase + rr;
            if (R < NN) {
                size_t idx = (size_t)R * 128 + C;
                float v = acc[cb][rr] + bb;
                if (DOELU) v = (v > 0.f) ? v : expm1f(v);
                if (OUTF32) ((float*)outv)[idx] = v;
                else        ((unsigned short*)outv)[idx] = f2bf(v);
            }
        }
    }
}

template<int DUAL, int DOELU, int OUTF32, int NOBIAS, int BIAS2>
__global__ __launch_bounds__(256)
void k_mm(const unsigned short* __restrict__ A, const unsigned short* __restrict__ A2,
          const short* __restrict__ Wp, const short* __restrict__ Wp2,
          const float* __restrict__ bias, const float* __restrict__ bias2,
          void* outv) {
    __shared__ short sMem[16384];
    gemm_body<DUAL, DOELU, OUTF32, NOBIAS, BIAS2>(blockIdx.x, A, A2, Wp, Wp2,
                                                  bias, bias2, outv, sMem, sMem + 8192);
}

// ---------------- mega1: block-owned scatter || T1 || C1 || S1 ----------------
// scatter: block b owns dst range [b*NPB, b*NPB+NPB); LDS cursors; col_idx lines
//          written by exactly one block -> no cross-XCD write amplification.
// T1 = hB@Wneigh1 -> B1 ; C1 = hB@Wself1 -> d_out (bf16 scratch) ; S1 = ELU(hB@Wsk1+b) -> B2

__global__ __launch_bounds__(256)
void k_mega1(const int* __restrict__ src, const int* __restrict__ dst,
             const int* __restrict__ row_start, int* __restrict__ col_idx,
             const unsigned short* __restrict__ hB, const short* __restrict__ wpk,
             const float* __restrict__ bsk1,
             unsigned short* __restrict__ T1out, unsigned short* __restrict__ C1out,
             unsigned short* __restrict__ S1out) {
    __shared__ short sMem[16384];
    int bid = blockIdx.x;
    if (bid < SCB) {
        int* lcur = (int*)sMem;          // [NPB]
        int* rs   = lcur + NPB;          // [NPB]
        const int t = threadIdx.x;
        const int n0 = bid * NPB;
        const int n1 = (n0 + NPB < NN) ? n0 + NPB : NN;
        const int nn = n1 - n0;
        for (int i = t; i < nn; i += 256) { lcur[i] = 0; rs[i] = row_start[n0 + i]; }
        __syncthreads();
        if (n0 >= NN) return;
        // scan all edges, int4-vectorized (NE/4 = 200000 int4)
        const int4* d4p = (const int4*)dst;
#pragma unroll 2
        for (int i = 0; i < 781; ++i) {
            int idx4 = t + i * 256;
            int4 d4 = d4p[idx4];
            int e0 = idx4 * 4;
#pragma unroll
            for (int j = 0; j < 4; ++j) {
                int d = (j == 0) ? d4.x : (j == 1) ? d4.y : (j == 2) ? d4.z : d4.w;
                if (d >= n0 && d < n1) {
                    int slot = atomicAdd(&lcur[d - n0], 1);
                    col_idx[rs[d - n0] + slot] = src[e0 + j];
                }
            }
        }
        if (t < 64) {
            int idx4 = t + 781 * 256;
            int4 d4 = d4p[idx4];
            int e0 = idx4 * 4;
#pragma unroll
            for (int j = 0; j < 4; ++j) {
                int d = (j == 0) ? d4.x : (j == 1) ? d4.y : (j == 2) ? d4.z : d4.w;
                if (d >= n0 && d < n1) {
                    int slot = atomicAdd(&lcur[d - n0], 1);
                    col_idx[rs[d - n0] + slot] = src[e0 + j];
                }
            }
        }
    } else if (bid < SCB + NT) {         // T1 (no bias)
        gemm_body<0, 0, 0, 1, 0>(bid - SCB, hB, nullptr, wpk + 3 * 16384, nullptr,
                                 nullptr, nullptr, T1out, sMem, sMem + 8192);
    } else if (bid < SCB + 2 * NT) {     // C1 (no bias)
        gemm_body<0, 0, 0, 1, 0>(bid - SCB - NT, hB, nullptr, wpk + 2 * 16384, nullptr,
                                 nullptr, nullptr, C1out, sMem, sMem + 8192);
    } else {                             // S1 = ELU(hB@Wsk1 + bsk1)
        gemm_body<0, 1, 0, 0, 0>(bid - SCB - 2 * NT, hB, nullptr, wpk, nullptr,
                                 bsk1, nullptr, S1out, sMem, sMem + 8192);
    }
}

// ---------------- agg1x: X1 = ELU(C1 + mean(T1) + bc)  (fused conv1) ----------------

__global__ __launch_bounds__(256)
void k_agg1x(const unsigned short* __restrict__ T1, const int* __restrict__ row_start,
             const int* __restrict__ col_idx, const unsigned short* __restrict__ C1,
             const float* __restrict__ bc, unsigned short* __restrict__ X1out) {
    int node = (blockIdx.x * 256 + threadIdx.x) >> 6;
    int lane = threadIdx.x & 63;
    if (node >= NN) return;
    const int beg = row_start[node], end = row_start[node + 1];
    const size_t lo = (size_t)(lane * 2);
    float sx = 0.f, sy = 0.f;
    int j = beg;
#pragma unroll 1
    for (; j + 8 <= end; j += 8) {
        int s[8];
#pragma unroll
        for (int u = 0; u < 8; ++u) s[u] = col_idx[j + u];
        unsigned v[8];
#pragma unroll
        for (int u = 0; u < 8; ++u)
            v[u] = *(const unsigned*)&T1[(size_t)s[u] * 128 + lo];
#pragma unroll
        for (int u = 0; u < 8; ++u) {
            sx += bf2f((unsigned short)(v[u] & 0xffff));
            sy += bf2f((unsigned short)(v[u] >> 16));
        }
    }
#pragma unroll 1
    for (; j < end; ++j) {
        int s = col_idx[j];
        unsigned v = *(const unsigned*)&T1[(size_t)s * 128 + lo];
        sx += bf2f((unsigned short)(v & 0xffff));
        sy += bf2f((unsigned short)(v >> 16));
    }
    float inv = 1.0f / fmaxf((float)(end - beg), 1.0f);
    unsigned c = *(const unsigned*)&C1[(size_t)node * 128 + lo];
    float x = sx * inv + bf2f((unsigned short)(c & 0xffff)) + bc[lane * 2];
    float y = sy * inv + bf2f((unsigned short)(c >> 16)) + bc[lane * 2 + 1];
    x = (x > 0.f) ? x : expm1f(x);
    y = (y > 0.f) ? y : expm1f(y);
    unsigned o = (unsigned)f2bf(x) | ((unsigned)f2bf(y) << 16);
    *(unsigned*)&X1out[(size_t)node * 128 + lo] = o;
}

// ---------------- mega3: outP = X3@Wself2 + S1@Wsk2 + (bconv2+bsk2) || T2 = X3@Wneigh2 ----------------

__global__ __launch_bounds__(256)
void k_mega3(const unsigned short* __restrict__ X3, const unsigned short* __restrict__ S1,
             const short* __restrict__ wpk, const float* __restrict__ bconv2,
             const float* __restrict__ bsk2, float* __restrict__ outP,
             unsigned short* __restrict__ T2out) {
    __shared__ short sMem[16384];
    int bid = blockIdx.x;
    if (bid < NT) {                      // outP (dual, f32, combined bias)
        gemm_body<1, 0, 1, 0, 1>(bid, X3, S1, wpk + 6 * 16384, wpk + 1 * 16384,
                                 bconv2, bsk2, outP, sMem, sMem + 8192);
    } else {                             // T2 (no bias)
        gemm_body<0, 0, 0, 1, 0>(bid - NT, X3, nullptr, wpk + 7 * 16384, nullptr,
                                 nullptr, nullptr, T2out, sMem, sMem + 8192);
    }
}

// ---------------- aggf: out += mean(T2)  (f32 RMW, own rows only) ----------------

__global__ __launch_bounds__(256)
void k_aggf(const unsigned short* __restrict__ T2, const int* __restrict__ row_start,
            const int* __restrict__ col_idx, float* __restrict__ out) {
    int node = (blockIdx.x * 256 + threadIdx.x) >> 6;
    int lane = threadIdx.x & 63;
    if (node >= NN) return;
    const int beg = row_start[node], end = row_start[node + 1];
    const size_t lo = (size_t)(lane * 2);
    float sx = 0.f, sy = 0.f;
    int j = beg;
#pragma unroll 1
    for (; j + 8 <= end; j += 8) {
        int s[8];
#pragma unroll
        for (int u = 0; u < 8; ++u) s[u] = col_idx[j + u];
        unsigned v[8];
#pragma unroll
        for (int u = 0; u < 8; ++u)
            v[u] = *(const unsigned*)&T2[(size_t)s[u] * 128 + lo];
#pragma unroll
        for (int u = 0; u < 8; ++u) {
            sx += bf2f((unsigned short)(v[u] & 0xffff));
            sy += bf2f((unsigned short)(v[u] >> 16));
        }
    }
#pragma unroll 1
    for (; j < end; ++j) {
        int s = col_idx[j];
        unsigned v = *(const unsigned*)&T2[(size_t)s * 128 + lo];
        sx += bf2f((unsigned short)(v & 0xffff));
        sy += bf2f((unsigned short)(v >> 16));
    }
    float inv = 1.0f / fmaxf((float)(end - beg), 1.0f);
    float2* op = (float2*)&out[(size_t)node * 128 + lo];
    float2 v = *op;
    v.x += sx * inv;
    v.y += sy * inv;
    *op = v;
}

// ---------------- launch ----------------

extern "C" void kernel_launch(void* const* d_in, const int* in_sizes, int n_in,
                              void* d_out, int out_size, void* d_ws, size_t ws_size,
                              hipStream_t stream) {
    const float* h        = (const float*)d_in[0];
    const int*   src      = (const int*)d_in[1];
    const int*   dst      = (const int*)d_in[2];
    const float* W_skip1  = (const float*)d_in[3];
    const float* b_skip1  = (const float*)d_in[4];
    const float* W_skip2  = (const float*)d_in[5];
    const float* b_skip2  = (const float*)d_in[6];
    const float* W_self1  = (const float*)d_in[7];
    const float* W_neigh1 = (const float*)d_in[8];
    const float* b_conv1  = (const float*)d_in[9];
    const float* W_si1    = (const float*)d_in[10];
    const float* b_si1    = (const float*)d_in[11];
    const float* W_si2    = (const float*)d_in[12];
    const float* b_si2    = (const float*)d_in[13];
    const float* W_self2  = (const float*)d_in[14];
    const float* W_neigh2 = (const float*)d_in[15];
    const float* b_conv2  = (const float*)d_in[16];
    float* out = (float*)d_out;

    char* ws = (char*)d_ws;
    int* deg       = (int*)ws;            // [50048]
    int* cursor    = deg + 50048;         // [50048] (unused, layout kept)
    int* row_start = deg + 100096;        // [50001] (padded to 150208)
    int* partials  = deg + 150208;        // [64]
    int* col_idx   = deg + 150272;        // [800000] -> ends at byte 3801088
    short* wpk          = (short*)(ws + 3801088);            // 8 x 16384 bf16
    unsigned short* hB  = (unsigned short*)(ws + 4063232);   // h -> X1 -> X3
    unsigned short* B1  = (unsigned short*)(ws + 16863232);  // T1 -> Y1 -> T2
    unsigned short* B2  = (unsigned short*)(ws + 29663232);  // S1
    unsigned short* C1s = (unsigned short*)d_out;            // C1 bf16 scratch (dead before f32 writes)

    (void)cursor;
    hipMemsetAsync(ws, 0, 50048 * sizeof(int), stream);

    // cvt | hist | packW
    k_prep<<<6258, 256, 0, stream>>>(h, hB, dst, deg,
                                     W_skip1, W_skip2, W_self1, W_neigh1,
                                     W_si1, W_si2, W_self2, W_neigh2, wpk);
    k_scan_part<<<49, 1024, 0, stream>>>(deg, partials);
    k_scan_top<<<1, 64, 0, stream>>>(partials, row_start, 49);
    k_scan_final<<<49, 1024, 0, stream>>>(deg, partials, row_start);

    // scatter || T1 || C1 || S1
    k_mega1<<<SCB + 3 * NT, 256, 0, stream>>>(src, dst, row_start, col_idx,
                                              hB, wpk, b_skip1, B1, C1s, B2);

    // X1 = ELU(C1 + mean(T1) + bc) -> hB   (fused conv1)
    k_agg1x<<<12500, 256, 0, stream>>>(B1, row_start, col_idx, C1s, b_conv1, hB);

    // si1: Y1 = ELU(X1@Wsi1+b) -> B1
    k_mm<0, 1, 0, 0, 0><<<NT, 256, 0, stream>>>(hB, nullptr, wpk + 4 * 16384, nullptr,
                                                b_si1, nullptr, B1);
    // si2: X3 = ELU(Y1@Wsi2+b) -> hB
    k_mm<0, 1, 0, 0, 0><<<NT, 256, 0, stream>>>(B1, nullptr, wpk + 5 * 16384, nullptr,
                                                b_si2, nullptr, hB);

    // outP = X3@Wself2 + S1@Wsk2 + (bconv2+bsk2) -> f32 out || T2 = X3@Wneigh2 -> B1
    k_mega3<<<2 * NT, 256, 0, stream>>>(hB, B2, wpk, b_conv2, b_skip2, out, B1);

    // out += mean(T2)
    k_aggf<<<12500, 256, 0, stream>>>(B1, row_start, col_idx, out);
}

// Round 11
// 247.625 us; speedup vs baseline: 2.0067x; 2.0067x over previous
//
#include <hip/hip_runtime.h>
#include <math.h>

#define NN 50000
#define NE 800000
#define NRT 782          // row tiles of 64
#define NT  (NRT * 2)    // x2 col-halves = 1564 blocks per GEMM
#define SB  3125         // scatter blocks (NE/256)

typedef __attribute__((ext_vector_type(8))) short short8;
typedef __attribute__((ext_vector_type(4))) float floatx4;

#define AS1 __attribute__((address_space(1)))
#define AS3 __attribute__((address_space(3)))

__device__ __forceinline__ unsigned short f2bf(float f) {
    unsigned u = __float_as_uint(f);
    unsigned r = (u + 0x7fff + ((u >> 16) & 1)) >> 16;
    return (unsigned short)r;
}
__device__ __forceinline__ float bf2f(unsigned short h) {
    return __uint_as_float(((unsigned)h) << 16);
}

// ---------------- CSR scans ----------------

__global__ void k_scan_part(const int* __restrict__ deg, int* __restrict__ partials) {
    __shared__ int s[1024];
    int idx = blockIdx.x * 1024 + threadIdx.x;
    s[threadIdx.x] = (idx < NN) ? deg[idx] : 0;
    for (int off = 512; off > 0; off >>= 1) {
        __syncthreads();
        if (threadIdx.x < off) s[threadIdx.x] += s[threadIdx.x + off];
    }
    if (threadIdx.x == 0) partials[blockIdx.x] = s[0];
}

__global__ void k_scan_top(int* __restrict__ partials, int* __restrict__ row_start, int n) {
    int lane = threadIdx.x;
    int orig = (lane < n) ? partials[lane] : 0;
    int v = orig;
    for (int off = 1; off < 64; off <<= 1) {
        int u = __shfl_up(v, off, 64);
        if (lane >= off) v += u;
    }
    if (lane < n) partials[lane] = v - orig;   // exclusive
    if (lane == 63) row_start[NN] = v;
}

__global__ void k_scan_final(const int* __restrict__ deg, const int* __restrict__ partials,
                             int* __restrict__ row_start) {
    __shared__ int s[1024];
    int idx = blockIdx.x * 1024 + threadIdx.x;
    int v = (idx < NN) ? deg[idx] : 0;
    s[threadIdx.x] = v;
    for (int off = 1; off < 1024; off <<= 1) {
        __syncthreads();
        int tmp = (threadIdx.x >= off) ? s[threadIdx.x - off] : 0;
        __syncthreads();
        s[threadIdx.x] += tmp;
    }
    if (idx < NN) row_start[idx] = partials[blockIdx.x] + s[threadIdx.x] - v;
}

// ---------------- prep: cvt (h->bf16) | hist | packW ----------------

__global__ __launch_bounds__(256)
void k_prep(const float* __restrict__ h, unsigned short* __restrict__ hB,
            const int* __restrict__ dst, int* __restrict__ deg,
            const float* w0, const float* w1, const float* w2, const float* w3,
            const float* w4, const float* w5, const float* w6, const float* w7,
            short* __restrict__ wpk) {
    int bid = blockIdx.x;
    if (bid < 3125) {              // cvt
        int i = (bid * 256 + threadIdx.x) * 8;
        float4 a = *(const float4*)&h[i];
        float4 b = *(const float4*)&h[i + 4];
        short8 v;
        v[0] = (short)f2bf(a.x); v[1] = (short)f2bf(a.y);
        v[2] = (short)f2bf(a.z); v[3] = (short)f2bf(a.w);
        v[4] = (short)f2bf(b.x); v[5] = (short)f2bf(b.y);
        v[6] = (short)f2bf(b.z); v[7] = (short)f2bf(b.w);
        *(short8*)&hB[i] = v;
    } else if (bid < 6250) {       // hist
        int e = (bid - 3125) * 256 + threadIdx.x;
        if (e < NE) atomicAdd(&deg[dst[e]], 1);
    } else {                       // packW, 8 blocks
        int wb = bid - 6250;
        const float* W;
        switch (wb) {
            case 0: W = w0; break; case 1: W = w1; break;
            case 2: W = w2; break; case 3: W = w3; break;
            case 4: W = w4; break; case 5: W = w5; break;
            case 6: W = w6; break; default: W = w7; break;
        }
        short* dstp = wpk + (size_t)wb * 16384;
#pragma unroll
        for (int i = 0; i < 8; ++i) {
            int q = threadIdx.x + i * 256;
            int cb = q >> 8, ks = (q >> 6) & 3, lane = q & 63;
            int n = lane & 15, g = lane >> 4;
            int col = cb * 16 + n, krow = ks * 32 + g * 8;
            short8 v;
#pragma unroll
            for (int j = 0; j < 8; ++j)
                v[j] = (short)f2bf(W[(krow + j) * 128 + col]);
            *(short8*)&dstp[q * 8] = v;
        }
    }
}

// ---------------- GEMM body: 64x64 tile, 4 waves, wave = 16 rows ----------------

template<int DUAL, int DOELU, int OUTF32, int NOBIAS, int BIAS2>
__device__ __forceinline__ void gemm_body(
        int bid,
        const unsigned short* __restrict__ A, const unsigned short* __restrict__ A2,
        const short* __restrict__ Wp, const short* __restrict__ Wp2,
        const float* __restrict__ bias, const float* __restrict__ bias2,
        void* outv, short* sW, short* sA) {
    const int t = threadIdx.x;
    const int wv = t >> 6, lane = t & 63;
    const int rb = bid >> 1, ct = bid & 1;
    const int row0 = rb * 64, col0 = ct * 64;
    const int m = lane & 15, g = lane >> 4;

    floatx4 acc[4];
#pragma unroll
    for (int cb = 0; cb < 4; ++cb) acc[cb] = (floatx4){0.f, 0.f, 0.f, 0.f};

    const int npass = DUAL ? 2 : 1;
    for (int pass = 0; pass < npass; ++pass) {
        const unsigned short* Ac = pass ? A2 : A;
        const short* Wc = (pass ? Wp2 : Wp) + ct * 8192;   // col-half of packed W
        __syncthreads();
#pragma unroll
        for (int i = 0; i < 4; ++i) {   // stage W: 1024 x 16B linear
            int cbase = (i * 4 + wv) * 64;
            __builtin_amdgcn_global_load_lds(
                (const AS1 unsigned int*)(Wc + (size_t)(cbase + lane) * 8),
                (AS3 unsigned int*)(sW + cbase * 8), 16, 0, 0);
        }
#pragma unroll
        for (int i = 0; i < 4; ++i) {   // stage A: swizzled source
            int cbase = (i * 4 + wv) * 64;
            int id = cbase + lane;
            int r = id >> 4, cs = id & 15;
            int rg = row0 + r; if (rg >= NN) rg = NN - 1;
            int csrc = cs ^ (r & 7);
            __builtin_amdgcn_global_load_lds(
                (const AS1 unsigned int*)(Ac + (size_t)rg * 128 + csrc * 8),
                (AS3 unsigned int*)(sA + cbase * 8), 16, 0, 0);
        }
        asm volatile("s_waitcnt vmcnt(0)" ::: "memory");
        __builtin_amdgcn_sched_barrier(0);
        __syncthreads();

        const int r0 = wv * 16;
#pragma unroll
        for (int ks = 0; ks < 4; ++ks) {
            int cxor = (ks * 4 + g) ^ (m & 7);
            short8 af = *(const short8*)&sA[((r0 + m) * 16 + cxor) * 8];
#pragma unroll
            for (int cb = 0; cb < 4; ++cb) {
                short8 bf = *(const short8*)&sW[((cb * 4 + ks) * 64 + lane) * 8];
                acc[cb] = __builtin_amdgcn_mfma_f32_16x16x32_bf16(af, bf, acc[cb], 0, 0, 0);
            }
        }
    }

    // epilogue: C/D layout col=lane&15, row=(lane>>4)*4+reg
    const int rowbase = row0 + wv * 16 + g * 4;
#pragma unroll
    for (int cb = 0; cb < 4; ++cb) {
        int C = col0 + cb * 16 + m;
        float bb = NOBIAS ? 0.f : bias[C];
        if (BIAS2) bb += bias2[C];
#pragma unroll
        for (int rr = 0; rr < 4; ++rr) {
            int R = rowbase + rr;
            if (R < NN) {
                size_t idx = (size_t)R * 128 + C;
                float v = acc[cb][rr] + bb;
                if (DOELU) v = (v > 0.f) ? v : expm1f(v);
                if (OUTF32) ((float*)outv)[idx] = v;
                else        ((unsigned short*)outv)[idx] = f2bf(v);
            }
        }
    }
}

template<int DUAL, int DOELU, int OUTF32, int NOBIAS, int BIAS2>
__global__ __launch_bounds__(256)
void k_mm(const unsigned short* __restrict__ A, const unsigned short* __restrict__ A2,
          const short* __restrict__ Wp, const short* __restrict__ Wp2,
          const float* __restrict__ bias, const float* __restrict__ bias2,
          void* outv) {
    __shared__ short sMem[16384];
    gemm_body<DUAL, DOELU, OUTF32, NOBIAS, BIAS2>(blockIdx.x, A, A2, Wp, Wp2,
                                                  bias, bias2, outv, sMem, sMem + 8192);
}

// ---------------- mega1: scatter || T1 || C1 || S1 ----------------
// scatter: global-atomic cursor (proven r9 form)
// T1 = hB@Wneigh1 -> B1 ; C1 = hB@Wself1 -> d_out bf16 scratch ; S1 = ELU(hB@Wsk1+b) -> B2

__global__ __launch_bounds__(256)
void k_mega1(const int* __restrict__ src, const int* __restrict__ dst,
             const int* __restrict__ row_start, int* __restrict__ cursor,
             int* __restrict__ col_idx,
             const unsigned short* __restrict__ hB, const short* __restrict__ wpk,
             const float* __restrict__ bsk1,
             unsigned short* __restrict__ T1out, unsigned short* __restrict__ C1out,
             unsigned short* __restrict__ S1out) {
    __shared__ short sMem[16384];
    int bid = blockIdx.x;
    if (bid < SB) {
        int e = bid * 256 + threadIdx.x;
        if (e < NE) {
            int d = dst[e];
            int slot = atomicAdd(&cursor[d], 1);
            col_idx[row_start[d] + slot] = src[e];
        }
    } else if (bid < SB + NT) {          // T1 = hB@Wneigh1 (no bias)
        gemm_body<0, 0, 0, 1, 0>(bid - SB, hB, nullptr, wpk + 3 * 16384, nullptr,
                                 nullptr, nullptr, T1out, sMem, sMem + 8192);
    } else if (bid < SB + 2 * NT) {      // C1 = hB@Wself1 (no bias)
        gemm_body<0, 0, 0, 1, 0>(bid - SB - NT, hB, nullptr, wpk + 2 * 16384, nullptr,
                                 nullptr, nullptr, C1out, sMem, sMem + 8192);
    } else {                             // S1 = ELU(hB@Wsk1 + bsk1)
        gemm_body<0, 1, 0, 0, 0>(bid - SB - 2 * NT, hB, nullptr, wpk, nullptr,
                                 bsk1, nullptr, S1out, sMem, sMem + 8192);
    }
}

// ---------------- agg1x: X1 = ELU(C1 + mean(T1) + bc)  (fused conv1) ----------------

__global__ __launch_bounds__(256)
void k_agg1x(const unsigned short* __restrict__ T1, const int* __restrict__ row_start,
             const int* __restrict__ col_idx, const unsigned short* __restrict__ C1,
             const float* __restrict__ bc, unsigned short* __restrict__ X1out) {
    int node = (blockIdx.x * 256 + threadIdx.x) >> 6;
    int lane = threadIdx.x & 63;
    if (node >= NN) return;
    const int beg = row_start[node], end = row_start[node + 1];
    const size_t lo = (size_t)(lane * 2);
    float sx = 0.f, sy = 0.f;
    int j = beg;
#pragma unroll 1
    for (; j + 8 <= end; j += 8) {
        int s[8];
#pragma unroll
        for (int u = 0; u < 8; ++u) s[u] = col_idx[j + u];
        unsigned v[8];
#pragma unroll
        for (int u = 0; u < 8; ++u)
            v[u] = *(const unsigned*)&T1[(size_t)s[u] * 128 + lo];
#pragma unroll
        for (int u = 0; u < 8; ++u) {
            sx += bf2f((unsigned short)(v[u] & 0xffff));
            sy += bf2f((unsigned short)(v[u] >> 16));
        }
    }
#pragma unroll 1
    for (; j < end; ++j) {
        int s = col_idx[j];
        unsigned v = *(const unsigned*)&T1[(size_t)s * 128 + lo];
        sx += bf2f((unsigned short)(v & 0xffff));
        sy += bf2f((unsigned short)(v >> 16));
    }
    float inv = 1.0f / fmaxf((float)(end - beg), 1.0f);
    unsigned c = *(const unsigned*)&C1[(size_t)node * 128 + lo];
    float x = sx * inv + bf2f((unsigned short)(c & 0xffff)) + bc[lane * 2];
    float y = sy * inv + bf2f((unsigned short)(c >> 16)) + bc[lane * 2 + 1];
    x = (x > 0.f) ? x : expm1f(x);
    y = (y > 0.f) ? y : expm1f(y);
    unsigned o = (unsigned)f2bf(x) | ((unsigned)f2bf(y) << 16);
    *(unsigned*)&X1out[(size_t)node * 128 + lo] = o;
}

// ---------------- mega3: outP = X3@Wself2 + S1@Wsk2 + (bconv2+bsk2) || T2 = X3@Wneigh2 ----------------

__global__ __launch_bounds__(256)
void k_mega3(const unsigned short* __restrict__ X3, const unsigned short* __restrict__ S1,
             const short* __restrict__ wpk, const float* __restrict__ bconv2,
             const float* __restrict__ bsk2, float* __restrict__ outP,
             unsigned short* __restrict__ T2out) {
    __shared__ short sMem[16384];
    int bid = blockIdx.x;
    if (bid < NT) {                      // outP (dual, f32, combined bias)
        gemm_body<1, 0, 1, 0, 1>(bid, X3, S1, wpk + 6 * 16384, wpk + 1 * 16384,
                                 bconv2, bsk2, outP, sMem, sMem + 8192);
    } else {                             // T2 (no bias)
        gemm_body<0, 0, 0, 1, 0>(bid - NT, X3, nullptr, wpk + 7 * 16384, nullptr,
                                 nullptr, nullptr, T2out, sMem, sMem + 8192);
    }
}

// ---------------- aggf: out += mean(T2)  (f32 RMW, own rows only) ----------------

__global__ __launch_bounds__(256)
void k_aggf(const unsigned short* __restrict__ T2, const int* __restrict__ row_start,
            const int* __restrict__ col_idx, float* __restrict__ out) {
    int node = (blockIdx.x * 256 + threadIdx.x) >> 6;
    int lane = threadIdx.x & 63;
    if (node >= NN) return;
    const int beg = row_start[node], end = row_start[node + 1];
    const size_t lo = (size_t)(lane * 2);
    float sx = 0.f, sy = 0.f;
    int j = beg;
#pragma unroll 1
    for (; j + 8 <= end; j += 8) {
        int s[8];
#pragma unroll
        for (int u = 0; u < 8; ++u) s[u] = col_idx[j + u];
        unsigned v[8];
#pragma unroll
        for (int u = 0; u < 8; ++u)
            v[u] = *(const unsigned*)&T2[(size_t)s[u] * 128 + lo];
#pragma unroll
        for (int u = 0; u < 8; ++u) {
            sx += bf2f((unsigned short)(v[u] & 0xffff));
            sy += bf2f((unsigned short)(v[u] >> 16));
        }
    }
#pragma unroll 1
    for (; j < end; ++j) {
        int s = col_idx[j];
        unsigned v = *(const unsigned*)&T2[(size_t)s * 128 + lo];
        sx += bf2f((unsigned short)(v & 0xffff));
        sy += bf2f((unsigned short)(v >> 16));
    }
    float inv = 1.0f / fmaxf((float)(end - beg), 1.0f);
    float2* op = (float2*)&out[(size_t)node * 128 + lo];
    float2 v = *op;
    v.x += sx * inv;
    v.y += sy * inv;
    *op = v;
}

// ---------------- launch ----------------

extern "C" void kernel_launch(void* const* d_in, const int* in_sizes, int n_in,
                              void* d_out, int out_size, void* d_ws, size_t ws_size,
                              hipStream_t stream) {
    const float* h        = (const float*)d_in[0];
    const int*   src      = (const int*)d_in[1];
    const int*   dst      = (const int*)d_in[2];
    const float* W_skip1  = (const float*)d_in[3];
    const float* b_skip1  = (const float*)d_in[4];
    const float* W_skip2  = (const float*)d_in[5];
    const float* b_skip2  = (const float*)d_in[6];
    const float* W_self1  = (const float*)d_in[7];
    const float* W_neigh1 = (const float*)d_in[8];
    const float* b_conv1  = (const float*)d_in[9];
    const float* W_si1    = (const float*)d_in[10];
    const float* b_si1    = (const float*)d_in[11];
    const float* W_si2    = (const float*)d_in[12];
    const float* b_si2    = (const float*)d_in[13];
    const float* W_self2  = (const float*)d_in[14];
    const float* W_neigh2 = (const float*)d_in[15];
    const float* b_conv2  = (const float*)d_in[16];
    float* out = (float*)d_out;

    char* ws = (char*)d_ws;
    int* deg       = (int*)ws;            // [50048]
    int* cursor    = deg + 50048;         // [50048]
    int* row_start = deg + 100096;        // [50001] (padded to 150208)
    int* partials  = deg + 150208;        // [64]
    int* col_idx   = deg + 150272;        // [800000] -> ends at byte 3801088
    short* wpk          = (short*)(ws + 3801088);            // 8 x 16384 bf16
    unsigned short* hB  = (unsigned short*)(ws + 4063232);   // h -> X1 -> X3
    unsigned short* B1  = (unsigned short*)(ws + 16863232);  // T1 -> Y1 -> T2
    unsigned short* B2  = (unsigned short*)(ws + 29663232);  // S1
    unsigned short* C1s = (unsigned short*)d_out;            // C1 bf16 scratch (dead before f32 writes)

    hipMemsetAsync(ws, 0, 100096 * sizeof(int), stream);

    // cvt | hist | packW
    k_prep<<<6258, 256, 0, stream>>>(h, hB, dst, deg,
                                     W_skip1, W_skip2, W_self1, W_neigh1,
                                     W_si1, W_si2, W_self2, W_neigh2, wpk);
    k_scan_part<<<49, 1024, 0, stream>>>(deg, partials);
    k_scan_top<<<1, 64, 0, stream>>>(partials, row_start, 49);
    k_scan_final<<<49, 1024, 0, stream>>>(deg, partials, row_start);

    // scatter || T1 || C1 || S1
    k_mega1<<<SB + 3 * NT, 256, 0, stream>>>(src, dst, row_start, cursor, col_idx,
                                             hB, wpk, b_skip1, B1, C1s, B2);

    // X1 = ELU(C1 + mean(T1) + bc) -> hB   (fused conv1)
    k_agg1x<<<12500, 256, 0, stream>>>(B1, row_start, col_idx, C1s, b_conv1, hB);

    // si1: Y1 = ELU(X1@Wsi1+b) -> B1
    k_mm<0, 1, 0, 0, 0><<<NT, 256, 0, stream>>>(hB, nullptr, wpk + 4 * 16384, nullptr,
                                                b_si1, nullptr, B1);
    // si2: X3 = ELU(Y1@Wsi2+b) -> hB
    k_mm<0, 1, 0, 0, 0><<<NT, 256, 0, stream>>>(B1, nullptr, wpk + 5 * 16384, nullptr,
                                                b_si2, nullptr, hB);

    // outP = X3@Wself2 + S1@Wsk2 + (bconv2+bsk2) -> f32 out || T2 = X3@Wneigh2 -> B1
    k_mega3<<<2 * NT, 256, 0, stream>>>(hB, B2, wpk, b_conv2, b_skip2, out, B1);

    // out += mean(T2)
    k_aggf<<<12500, 256, 0, stream>>>(B1, row_start, col_idx, out);
}

// Round 12
// 226.007 us; speedup vs baseline: 2.1986x; 1.0957x over previous
//
#include <hip/hip_runtime.h>
#include <math.h>

#define NN 50000
#define NE 800000
#define NRT 782          // row tiles of 64
#define NT  (NRT * 2)    // x2 col-halves = 1564 blocks per GEMM
#define NB  128          // coarse dst-buckets
#define NPB2 391         // nodes per bucket (128*391 = 50048 >= NN)
#define EPB 2048         // edges per bucketize block
#define NBB 391          // bucketize blocks (ceil(NE/EPB))

typedef __attribute__((ext_vector_type(8))) short short8;
typedef __attribute__((ext_vector_type(4))) float floatx4;

#define AS1 __attribute__((address_space(1)))
#define AS3 __attribute__((address_space(3)))

__device__ __forceinline__ unsigned short f2bf(float f) {
    unsigned u = __float_as_uint(f);
    unsigned r = (u + 0x7fff + ((u >> 16) & 1)) >> 16;
    return (unsigned short)r;
}
__device__ __forceinline__ float bf2f(unsigned short h) {
    return __uint_as_float(((unsigned)h) << 16);
}

// ---------------- CSR scans ----------------

__global__ void k_scan_part(const int* __restrict__ deg, int* __restrict__ partials) {
    __shared__ int s[1024];
    int idx = blockIdx.x * 1024 + threadIdx.x;
    s[threadIdx.x] = (idx < NN) ? deg[idx] : 0;
    for (int off = 512; off > 0; off >>= 1) {
        __syncthreads();
        if (threadIdx.x < off) s[threadIdx.x] += s[threadIdx.x + off];
    }
    if (threadIdx.x == 0) partials[blockIdx.x] = s[0];
}

__global__ void k_scan_top(int* __restrict__ partials, int* __restrict__ row_start, int n) {
    int lane = threadIdx.x;
    int orig = (lane < n) ? partials[lane] : 0;
    int v = orig;
    for (int off = 1; off < 64; off <<= 1) {
        int u = __shfl_up(v, off, 64);
        if (lane >= off) v += u;
    }
    if (lane < n) partials[lane] = v - orig;   // exclusive
    if (lane == 63) row_start[NN] = v;
}

__global__ void k_scan_final(const int* __restrict__ deg, const int* __restrict__ partials,
                             int* __restrict__ row_start) {
    __shared__ int s[1024];
    int idx = blockIdx.x * 1024 + threadIdx.x;
    int v = (idx < NN) ? deg[idx] : 0;
    s[threadIdx.x] = v;
    for (int off = 1; off < 1024; off <<= 1) {
        __syncthreads();
        int tmp = (threadIdx.x >= off) ? s[threadIdx.x - off] : 0;
        __syncthreads();
        s[threadIdx.x] += tmp;
    }
    if (idx < NN) row_start[idx] = partials[blockIdx.x] + s[threadIdx.x] - v;
}

// gcur[b] = row_start[b*391]  (bucket write cursors)
__global__ void k_binit(const int* __restrict__ row_start, int* __restrict__ gcur) {
    int b = threadIdx.x;
    if (b < NB) gcur[b] = row_start[b * NPB2];
}

// ---------------- prep: cvt (h->bf16) | hist | packW ----------------

__global__ __launch_bounds__(256)
void k_prep(const float* __restrict__ h, unsigned short* __restrict__ hB,
            const int* __restrict__ dst, int* __restrict__ deg,
            const float* w0, const float* w1, const float* w2, const float* w3,
            const float* w4, const float* w5, const float* w6, const float* w7,
            short* __restrict__ wpk) {
    int bid = blockIdx.x;
    if (bid < 3125) {              // cvt
        int i = (bid * 256 + threadIdx.x) * 8;
        float4 a = *(const float4*)&h[i];
        float4 b = *(const float4*)&h[i + 4];
        short8 v;
        v[0] = (short)f2bf(a.x); v[1] = (short)f2bf(a.y);
        v[2] = (short)f2bf(a.z); v[3] = (short)f2bf(a.w);
        v[4] = (short)f2bf(b.x); v[5] = (short)f2bf(b.y);
        v[6] = (short)f2bf(b.z); v[7] = (short)f2bf(b.w);
        *(short8*)&hB[i] = v;
    } else if (bid < 6250) {       // hist
        int e = (bid - 3125) * 256 + threadIdx.x;
        if (e < NE) atomicAdd(&deg[dst[e]], 1);
    } else {                       // packW, 8 blocks
        int wb = bid - 6250;
        const float* W;
        switch (wb) {
            case 0: W = w0; break; case 1: W = w1; break;
            case 2: W = w2; break; case 3: W = w3; break;
            case 4: W = w4; break; case 5: W = w5; break;
            case 6: W = w6; break; default: W = w7; break;
        }
        short* dstp = wpk + (size_t)wb * 16384;
#pragma unroll
        for (int i = 0; i < 8; ++i) {
            int q = threadIdx.x + i * 256;
            int cb = q >> 8, ks = (q >> 6) & 3, lane = q & 63;
            int n = lane & 15, g = lane >> 4;
            int col = cb * 16 + n, krow = ks * 32 + g * 8;
            short8 v;
#pragma unroll
            for (int j = 0; j < 8; ++j)
                v[j] = (short)f2bf(W[(krow + j) * 128 + col]);
            *(short8*)&dstp[q * 8] = v;
        }
    }
}

// ---------------- bucketize: LDS-chunked reorder into 128 dst-buckets ----------------
// Bucket b's region in (bsrc,bdst) = [row_start[b*391], row_start[(b+1)*391]).

__global__ __launch_bounds__(256)
void k_bucket(const int* __restrict__ src, const int* __restrict__ dst,
              int* __restrict__ gcur, int* __restrict__ bsrc, int* __restrict__ bdst) {
    __shared__ int psrc[EPB];
    __shared__ int pdst[EPB];
    __shared__ int cnt[NB];
    __shared__ int ebase[NB];
    __shared__ int gbase[NB];
    const int t = threadIdx.x;
    const int e0 = blockIdx.x * EPB;
    const int M = (e0 + EPB <= NE) ? EPB : (NE - e0);

    if (t < NB) cnt[t] = 0;
    __syncthreads();

    int es[8], ed[8], rank[8];
#pragma unroll
    for (int i = 0; i < 8; ++i) {
        int idx = i * 256 + t;
        if (idx < M) {
            es[i] = src[e0 + idx];
            ed[i] = dst[e0 + idx];
            rank[i] = atomicAdd(&cnt[ed[i] / NPB2], 1);
        }
    }
    __syncthreads();
    // exclusive prefix over cnt[128] (Hillis-Steele on ebase)
    if (t < NB) ebase[t] = cnt[t];
    __syncthreads();
    for (int off = 1; off < NB; off <<= 1) {
        int v = 0;
        if (t < NB && t >= off) v = ebase[t - off];
        __syncthreads();
        if (t < NB) ebase[t] += v;
        __syncthreads();
    }
    if (t < NB) ebase[t] -= cnt[t];   // exclusive
    __syncthreads();
    // place pairs bucket-ordered in LDS
#pragma unroll
    for (int i = 0; i < 8; ++i) {
        int idx = i * 256 + t;
        if (idx < M) {
            int b = ed[i] / NPB2;
            int pos = ebase[b] + rank[i];
            psrc[pos] = es[i];
            pdst[pos] = ed[i];
        }
    }
    // reserve global runs
    if (t < NB && cnt[t] > 0) gbase[t] = atomicAdd(&gcur[t], cnt[t]);
    __syncthreads();
    // copy runs out (consecutive i within a bucket -> consecutive global slots)
#pragma unroll
    for (int i = 0; i < 8; ++i) {
        int idx = i * 256 + t;
        if (idx < M) {
            int d = pdst[idx];
            int b = d / NPB2;
            int gpos = gbase[b] + (idx - ebase[b]);
            bsrc[gpos] = psrc[idx];
            bdst[gpos] = d;
        }
    }
}

// ---------------- GEMM body: 64x64 tile, 4 waves, wave = 16 rows ----------------

template<int DUAL, int DOELU, int OUTF32, int NOBIAS, int BIAS2>
__device__ __forceinline__ void gemm_body(
        int bid,
        const unsigned short* __restrict__ A, const unsigned short* __restrict__ A2,
        const short* __restrict__ Wp, const short* __restrict__ Wp2,
        const float* __restrict__ bias, const float* __restrict__ bias2,
        void* outv, short* sW, short* sA) {
    const int t = threadIdx.x;
    const int wv = t >> 6, lane = t & 63;
    const int rb = bid >> 1, ct = bid & 1;
    const int row0 = rb * 64, col0 = ct * 64;
    const int m = lane & 15, g = lane >> 4;

    floatx4 acc[4];
#pragma unroll
    for (int cb = 0; cb < 4; ++cb) acc[cb] = (floatx4){0.f, 0.f, 0.f, 0.f};

    const int npass = DUAL ? 2 : 1;
    for (int pass = 0; pass < npass; ++pass) {
        const unsigned short* Ac = pass ? A2 : A;
        const short* Wc = (pass ? Wp2 : Wp) + ct * 8192;   // col-half of packed W
        __syncthreads();
#pragma unroll
        for (int i = 0; i < 4; ++i) {   // stage W: 1024 x 16B linear
            int cbase = (i * 4 + wv) * 64;
            __builtin_amdgcn_global_load_lds(
                (const AS1 unsigned int*)(Wc + (size_t)(cbase + lane) * 8),
                (AS3 unsigned int*)(sW + cbase * 8), 16, 0, 0);
        }
#pragma unroll
        for (int i = 0; i < 4; ++i) {   // stage A: swizzled source
            int cbase = (i * 4 + wv) * 64;
            int id = cbase + lane;
            int r = id >> 4, cs = id & 15;
            int rg = row0 + r; if (rg >= NN) rg = NN - 1;
            int csrc = cs ^ (r & 7);
            __builtin_amdgcn_global_load_lds(
                (const AS1 unsigned int*)(Ac + (size_t)rg * 128 + csrc * 8),
                (AS3 unsigned int*)(sA + cbase * 8), 16, 0, 0);
        }
        asm volatile("s_waitcnt vmcnt(0)" ::: "memory");
        __builtin_amdgcn_sched_barrier(0);
        __syncthreads();

        const int r0 = wv * 16;
#pragma unroll
        for (int ks = 0; ks < 4; ++ks) {
            int cxor = (ks * 4 + g) ^ (m & 7);
            short8 af = *(const short8*)&sA[((r0 + m) * 16 + cxor) * 8];
#pragma unroll
            for (int cb = 0; cb < 4; ++cb) {
                short8 bf = *(const short8*)&sW[((cb * 4 + ks) * 64 + lane) * 8];
                acc[cb] = __builtin_amdgcn_mfma_f32_16x16x32_bf16(af, bf, acc[cb], 0, 0, 0);
            }
        }
    }

    // epilogue: C/D layout col=lane&15, row=(lane>>4)*4+reg
    const int rowbase = row0 + wv * 16 + g * 4;
#pragma unroll
    for (int cb = 0; cb < 4; ++cb) {
        int C = col0 + cb * 16 + m;
        float bb = NOBIAS ? 0.f : bias[C];
        if (BIAS2) bb += bias2[C];
#pragma unroll
        for (int rr = 0; rr < 4; ++rr) {
            int R = rowbase + rr;
            if (R < NN) {
                size_t idx = (size_t)R * 128 + C;
                float v = acc[cb][rr] + bb;
                if (DOELU) v = (v > 0.f) ? v : expm1f(v);
                if (OUTF32) ((float*)outv)[idx] = v;
                else        ((unsigned short*)outv)[idx] = f2bf(v);
            }
        }
    }
}

template<int DUAL, int DOELU, int OUTF32, int NOBIAS, int BIAS2>
__global__ __launch_bounds__(256)
void k_mm(const unsigned short* __restrict__ A, const unsigned short* __restrict__ A2,
          const short* __restrict__ Wp, const short* __restrict__ Wp2,
          const float* __restrict__ bias, const float* __restrict__ bias2,
          void* outv) {
    __shared__ short sMem[16384];
    gemm_body<DUAL, DOELU, OUTF32, NOBIAS, BIAS2>(blockIdx.x, A, A2, Wp, Wp2,
                                                  bias, bias2, outv, sMem, sMem + 8192);
}

// ---------------- mega1: per-bucket scatter || T1 || C1 || S1 ----------------
// scatter pass-2: block b owns bucket b -> block-private contiguous col_idx window.

__global__ __launch_bounds__(256)
void k_mega1(const int* __restrict__ bsrc, const int* __restrict__ bdst,
             const int* __restrict__ row_start, int* __restrict__ col_idx,
             const unsigned short* __restrict__ hB, const short* __restrict__ wpk,
             const float* __restrict__ bsk1,
             unsigned short* __restrict__ T1out, unsigned short* __restrict__ C1out,
             unsigned short* __restrict__ S1out) {
    __shared__ short sMem[16384];
    int bid = blockIdx.x;
    if (bid < NB) {
        int* lcur = (int*)sMem;          // [NPB2]
        int* rs   = lcur + NPB2;         // [NPB2]
        const int t = threadIdx.x;
        const int n0 = bid * NPB2;
        const int n1 = (n0 + NPB2 < NN) ? n0 + NPB2 : NN;
        const int nn = n1 - n0;
        for (int i = t; i < nn; i += 256) { lcur[i] = 0; rs[i] = row_start[n0 + i]; }
        __syncthreads();
        const int estart = row_start[n0];
        const int eend   = row_start[n1];
        for (int e = estart + t; e < eend; e += 256) {
            int d = bdst[e] - n0;
            int slot = atomicAdd(&lcur[d], 1);
            col_idx[rs[d] + slot] = bsrc[e];
        }
    } else if (bid < NB + NT) {          // T1 = hB@Wneigh1 (no bias)
        gemm_body<0, 0, 0, 1, 0>(bid - NB, hB, nullptr, wpk + 3 * 16384, nullptr,
                                 nullptr, nullptr, T1out, sMem, sMem + 8192);
    } else if (bid < NB + 2 * NT) {      // C1 = hB@Wself1 (no bias)
        gemm_body<0, 0, 0, 1, 0>(bid - NB - NT, hB, nullptr, wpk + 2 * 16384, nullptr,
                                 nullptr, nullptr, C1out, sMem, sMem + 8192);
    } else {                             // S1 = ELU(hB@Wsk1 + bsk1)
        gemm_body<0, 1, 0, 0, 0>(bid - NB - 2 * NT, hB, nullptr, wpk, nullptr,
                                 bsk1, nullptr, S1out, sMem, sMem + 8192);
    }
}

// ---------------- agg1x: X1 = ELU(C1 + mean(T1) + bc)  (fused conv1) ----------------

__global__ __launch_bounds__(256)
void k_agg1x(const unsigned short* __restrict__ T1, const int* __restrict__ row_start,
             const int* __restrict__ col_idx, const unsigned short* __restrict__ C1,
             const float* __restrict__ bc, unsigned short* __restrict__ X1out) {
    int node = (blockIdx.x * 256 + threadIdx.x) >> 6;
    int lane = threadIdx.x & 63;
    if (node >= NN) return;
    const int beg = row_start[node], end = row_start[node + 1];
    const size_t lo = (size_t)(lane * 2);
    float sx = 0.f, sy = 0.f;
    int j = beg;
#pragma unroll 1
    for (; j + 8 <= end; j += 8) {
        int s[8];
#pragma unroll
        for (int u = 0; u < 8; ++u) s[u] = col_idx[j + u];
        unsigned v[8];
#pragma unroll
        for (int u = 0; u < 8; ++u)
            v[u] = *(const unsigned*)&T1[(size_t)s[u] * 128 + lo];
#pragma unroll
        for (int u = 0; u < 8; ++u) {
            sx += bf2f((unsigned short)(v[u] & 0xffff));
            sy += bf2f((unsigned short)(v[u] >> 16));
        }
    }
#pragma unroll 1
    for (; j < end; ++j) {
        int s = col_idx[j];
        unsigned v = *(const unsigned*)&T1[(size_t)s * 128 + lo];
        sx += bf2f((unsigned short)(v & 0xffff));
        sy += bf2f((unsigned short)(v >> 16));
    }
    float inv = 1.0f / fmaxf((float)(end - beg), 1.0f);
    unsigned c = *(const unsigned*)&C1[(size_t)node * 128 + lo];
    float x = sx * inv + bf2f((unsigned short)(c & 0xffff)) + bc[lane * 2];
    float y = sy * inv + bf2f((unsigned short)(c >> 16)) + bc[lane * 2 + 1];
    x = (x > 0.f) ? x : expm1f(x);
    y = (y > 0.f) ? y : expm1f(y);
    unsigned o = (unsigned)f2bf(x) | ((unsigned)f2bf(y) << 16);
    *(unsigned*)&X1out[(size_t)node * 128 + lo] = o;
}

// ---------------- mega3: outP = X3@Wself2 + S1@Wsk2 + (bconv2+bsk2) || T2 = X3@Wneigh2 ----------------

__global__ __launch_bounds__(256)
void k_mega3(const unsigned short* __restrict__ X3, const unsigned short* __restrict__ S1,
             const short* __restrict__ wpk, const float* __restrict__ bconv2,
             const float* __restrict__ bsk2, float* __restrict__ outP,
             unsigned short* __restrict__ T2out) {
    __shared__ short sMem[16384];
    int bid = blockIdx.x;
    if (bid < NT) {                      // outP (dual, f32, combined bias)
        gemm_body<1, 0, 1, 0, 1>(bid, X3, S1, wpk + 6 * 16384, wpk + 1 * 16384,
                                 bconv2, bsk2, outP, sMem, sMem + 8192);
    } else {                             // T2 (no bias)
        gemm_body<0, 0, 0, 1, 0>(bid - NT, X3, nullptr, wpk + 7 * 16384, nullptr,
                                 nullptr, nullptr, T2out, sMem, sMem + 8192);
    }
}

// ---------------- aggf: out += mean(T2)  (f32 RMW, own rows only) ----------------

__global__ __launch_bounds__(256)
void k_aggf(const unsigned short* __restrict__ T2, const int* __restrict__ row_start,
            const int* __restrict__ col_idx, float* __restrict__ out) {
    int node = (blockIdx.x * 256 + threadIdx.x) >> 6;
    int lane = threadIdx.x & 63;
    if (node >= NN) return;
    const int beg = row_start[node], end = row_start[node + 1];
    const size_t lo = (size_t)(lane * 2);
    float sx = 0.f, sy = 0.f;
    int j = beg;
#pragma unroll 1
    for (; j + 8 <= end; j += 8) {
        int s[8];
#pragma unroll
        for (int u = 0; u < 8; ++u) s[u] = col_idx[j + u];
        unsigned v[8];
#pragma unroll
        for (int u = 0; u < 8; ++u)
            v[u] = *(const unsigned*)&T2[(size_t)s[u] * 128 + lo];
#pragma unroll
        for (int u = 0; u < 8; ++u) {
            sx += bf2f((unsigned short)(v[u] & 0xffff));
            sy += bf2f((unsigned short)(v[u] >> 16));
        }
    }
#pragma unroll 1
    for (; j < end; ++j) {
        int s = col_idx[j];
        unsigned v = *(const unsigned*)&T2[(size_t)s * 128 + lo];
        sx += bf2f((unsigned short)(v & 0xffff));
        sy += bf2f((unsigned short)(v >> 16));
    }
    float inv = 1.0f / fmaxf((float)(end - beg), 1.0f);
    float2* op = (float2*)&out[(size_t)node * 128 + lo];
    float2 v = *op;
    v.x += sx * inv;
    v.y += sy * inv;
    *op = v;
}

// ---------------- launch ----------------

extern "C" void kernel_launch(void* const* d_in, const int* in_sizes, int n_in,
                              void* d_out, int out_size, void* d_ws, size_t ws_size,
                              hipStream_t stream) {
    const float* h        = (const float*)d_in[0];
    const int*   src      = (const int*)d_in[1];
    const int*   dst      = (const int*)d_in[2];
    const float* W_skip1  = (const float*)d_in[3];
    const float* b_skip1  = (const float*)d_in[4];
    const float* W_skip2  = (const float*)d_in[5];
    const float* b_skip2  = (const float*)d_in[6];
    const float* W_self1  = (const float*)d_in[7];
    const float* W_neigh1 = (const float*)d_in[8];
    const float* b_conv1  = (const float*)d_in[9];
    const float* W_si1    = (const float*)d_in[10];
    const float* b_si1    = (const float*)d_in[11];
    const float* W_si2    = (const float*)d_in[12];
    const float* b_si2    = (const float*)d_in[13];
    const float* W_self2  = (const float*)d_in[14];
    const float* W_neigh2 = (const float*)d_in[15];
    const float* b_conv2  = (const float*)d_in[16];
    float* out = (float*)d_out;

    char* ws = (char*)d_ws;
    int* deg       = (int*)ws;            // [50048]
    int* gcur      = deg + 50048;         // [128] bucket cursors (old cursor slot)
    int* row_start = deg + 100096;        // [50001] (padded to 150208)
    int* partials  = deg + 150208;        // [64]
    int* col_idx   = deg + 150272;        // [800000] -> ends at byte 3801088
    short* wpk          = (short*)(ws + 3801088);            // 8 x 16384 bf16
    unsigned short* hB  = (unsigned short*)(ws + 4063232);   // h -> X1 -> X3
    unsigned short* B1  = (unsigned short*)(ws + 16863232);  // T1 -> Y1 -> T2
    unsigned short* B2  = (unsigned short*)(ws + 29663232);  // S1
    int* bsrc           = (int*)(ws + 42463232);             // [800000]
    int* bdst           = (int*)(ws + 45663232);             // [800000] -> 48863232
    unsigned short* C1s = (unsigned short*)d_out;            // C1 bf16 scratch (dead before f32 writes)

    hipMemsetAsync(ws, 0, 50048 * sizeof(int), stream);

    // cvt | hist | packW
    k_prep<<<6258, 256, 0, stream>>>(h, hB, dst, deg,
                                     W_skip1, W_skip2, W_self1, W_neigh1,
                                     W_si1, W_si2, W_self2, W_neigh2, wpk);
    k_scan_part<<<49, 1024, 0, stream>>>(deg, partials);
    k_scan_top<<<1, 64, 0, stream>>>(partials, row_start, 49);
    k_scan_final<<<49, 1024, 0, stream>>>(deg, partials, row_start);
    k_binit<<<1, 128, 0, stream>>>(row_start, gcur);

    // LDS-chunked bucketize (coalesced run writes)
    k_bucket<<<NBB, 256, 0, stream>>>(src, dst, gcur, bsrc, bdst);

    // per-bucket scatter || T1 || C1 || S1
    k_mega1<<<NB + 3 * NT, 256, 0, stream>>>(bsrc, bdst, row_start, col_idx,
                                             hB, wpk, b_skip1, B1, C1s, B2);

    // X1 = ELU(C1 + mean(T1) + bc) -> hB   (fused conv1)
    k_agg1x<<<12500, 256, 0, stream>>>(B1, row_start, col_idx, C1s, b_conv1, hB);

    // si1: Y1 = ELU(X1@Wsi1+b) -> B1
    k_mm<0, 1, 0, 0, 0><<<NT, 256, 0, stream>>>(hB, nullptr, wpk + 4 * 16384, nullptr,
                                                b_si1, nullptr, B1);
    // si2: X3 = ELU(Y1@Wsi2+b) -> hB
    k_mm<0, 1, 0, 0, 0><<<NT, 256, 0, stream>>>(B1, nullptr, wpk + 5 * 16384, nullptr,
                                                b_si2, nullptr, hB);

    // outP = X3@Wself2 + S1@Wsk2 + (bconv2+bsk2) -> f32 out || T2 = X3@Wneigh2 -> B1
    k_mega3<<<2 * NT, 256, 0, stream>>>(hB, B2, wpk, b_conv2, b_skip2, out, B1);

    // out += mean(T2)
    k_aggf<<<12500, 256, 0, stream>>>(B1, row_start, col_idx, out);
}

// Round 13
// 199.459 us; speedup vs baseline: 2.4912x; 1.1331x over previous
//
#include <hip/hip_runtime.h>
#include <math.h>

#define NN 50000
#define NE 800000
#define NRT 782          // row tiles of 64
#define NT  (NRT * 2)    // x2 col-halves = 1564 blocks per GEMM
#define NB  128          // coarse dst-buckets
#define NPB2 391         // nodes per bucket (128*391 = 50048 >= NN)
#define EPB 2048         // edges per bucketize block
#define NBB 391          // bucketize blocks (ceil(NE/EPB))

typedef __attribute__((ext_vector_type(8))) short short8;
typedef __attribute__((ext_vector_type(4))) float floatx4;

#define AS1 __attribute__((address_space(1)))
#define AS3 __attribute__((address_space(3)))

__device__ __forceinline__ unsigned short f2bf(float f) {
    unsigned u = __float_as_uint(f);
    unsigned r = (u + 0x7fff + ((u >> 16) & 1)) >> 16;
    return (unsigned short)r;
}
__device__ __forceinline__ float bf2f(unsigned short h) {
    return __uint_as_float(((unsigned)h) << 16);
}

// ---------------- prep: cvt (h->bf16) | bucket-count | packW ----------------

__global__ __launch_bounds__(256)
void k_prep(const float* __restrict__ h, unsigned short* __restrict__ hB,
            const int* __restrict__ dst, int* __restrict__ bcnt,
            const float* w0, const float* w1, const float* w2, const float* w3,
            const float* w4, const float* w5, const float* w6, const float* w7,
            short* __restrict__ wpk) {
    int bid = blockIdx.x;
    const int t = threadIdx.x;
    if (bid < 3125) {              // cvt
        int i = (bid * 256 + t) * 8;
        float4 a = *(const float4*)&h[i];
        float4 b = *(const float4*)&h[i + 4];
        short8 v;
        v[0] = (short)f2bf(a.x); v[1] = (short)f2bf(a.y);
        v[2] = (short)f2bf(a.z); v[3] = (short)f2bf(a.w);
        v[4] = (short)f2bf(b.x); v[5] = (short)f2bf(b.y);
        v[6] = (short)f2bf(b.z); v[7] = (short)f2bf(b.w);
        *(short8*)&hB[i] = v;
    } else if (bid < 3125 + NBB) { // bucket-count (LDS histogram of 128 buckets)
        __shared__ int cnt[NB];
        if (t < NB) cnt[t] = 0;
        __syncthreads();
        int base = (bid - 3125) * EPB;
#pragma unroll
        for (int i = 0; i < 8; ++i) {
            int idx = base + i * 256 + t;
            if (idx < NE) atomicAdd(&cnt[dst[idx] / NPB2], 1);
        }
        __syncthreads();
        if (t < NB && cnt[t]) atomicAdd(&bcnt[t], cnt[t]);
    } else {                       // packW, 8 blocks
        int wb = bid - 3125 - NBB;
        const float* W;
        switch (wb) {
            case 0: W = w0; break; case 1: W = w1; break;
            case 2: W = w2; break; case 3: W = w3; break;
            case 4: W = w4; break; case 5: W = w5; break;
            case 6: W = w6; break; default: W = w7; break;
        }
        short* dstp = wpk + (size_t)wb * 16384;
#pragma unroll
        for (int i = 0; i < 8; ++i) {
            int q = t + i * 256;
            int cb = q >> 8, ks = (q >> 6) & 3, lane = q & 63;
            int n = lane & 15, g = lane >> 4;
            int col = cb * 16 + n, krow = ks * 32 + g * 8;
            short8 v;
#pragma unroll
            for (int j = 0; j < 8; ++j)
                v[j] = (short)f2bf(W[(krow + j) * 128 + col]);
            *(short8*)&dstp[q * 8] = v;
        }
    }
}

// ---------------- bscan: 128-wide prefix -> gcur (cursors) + bstart ----------------

__global__ void k_bscan(const int* __restrict__ bcnt, int* __restrict__ gcur,
                        int* __restrict__ bstart) {
    __shared__ int s[NB];
    int t = threadIdx.x;
    int c = bcnt[t];
    s[t] = c;
    __syncthreads();
    for (int off = 1; off < NB; off <<= 1) {
        int v = (t >= off) ? s[t - off] : 0;
        __syncthreads();
        s[t] += v;
        __syncthreads();
    }
    int excl = s[t] - c;
    gcur[t] = excl;
    bstart[t] = excl;
    if (t == NB - 1) bstart[NB] = s[NB - 1];   // = NE
}

// ---------------- bucketize: LDS-chunked reorder into 128 dst-buckets ----------------

__global__ __launch_bounds__(256)
void k_bucket(const int* __restrict__ src, const int* __restrict__ dst,
              int* __restrict__ gcur, int* __restrict__ bsrc, int* __restrict__ bdst) {
    __shared__ int psrc[EPB];
    __shared__ int pdst[EPB];
    __shared__ int cnt[NB];
    __shared__ int ebase[NB];
    __shared__ int gbase[NB];
    const int t = threadIdx.x;
    const int e0 = blockIdx.x * EPB;
    const int M = (e0 + EPB <= NE) ? EPB : (NE - e0);

    if (t < NB) cnt[t] = 0;
    __syncthreads();

    int es[8], ed[8], rank[8];
#pragma unroll
    for (int i = 0; i < 8; ++i) {
        int idx = i * 256 + t;
        if (idx < M) {
            es[i] = src[e0 + idx];
            ed[i] = dst[e0 + idx];
            rank[i] = atomicAdd(&cnt[ed[i] / NPB2], 1);
        }
    }
    __syncthreads();
    if (t < NB) ebase[t] = cnt[t];
    __syncthreads();
    for (int off = 1; off < NB; off <<= 1) {
        int v = 0;
        if (t < NB && t >= off) v = ebase[t - off];
        __syncthreads();
        if (t < NB) ebase[t] += v;
        __syncthreads();
    }
    if (t < NB) ebase[t] -= cnt[t];   // exclusive
    __syncthreads();
#pragma unroll
    for (int i = 0; i < 8; ++i) {
        int idx = i * 256 + t;
        if (idx < M) {
            int b = ed[i] / NPB2;
            int pos = ebase[b] + rank[i];
            psrc[pos] = es[i];
            pdst[pos] = ed[i];
        }
    }
    if (t < NB && cnt[t] > 0) gbase[t] = atomicAdd(&gcur[t], cnt[t]);
    __syncthreads();
#pragma unroll
    for (int i = 0; i < 8; ++i) {
        int idx = i * 256 + t;
        if (idx < M) {
            int d = pdst[idx];
            int b = d / NPB2;
            int gpos = gbase[b] + (idx - ebase[b]);
            bsrc[gpos] = psrc[idx];
            bdst[gpos] = d;
        }
    }
}

// ---------------- GEMM body: 64x64 tile, 4 waves, wave = 16 rows ----------------

template<int DUAL, int DOELU, int OUTF32, int NOBIAS, int BIAS2>
__device__ __forceinline__ void gemm_body(
        int bid,
        const unsigned short* __restrict__ A, const unsigned short* __restrict__ A2,
        const short* __restrict__ Wp, const short* __restrict__ Wp2,
        const float* __restrict__ bias, const float* __restrict__ bias2,
        void* outv, short* sW, short* sA) {
    const int t = threadIdx.x;
    const int wv = t >> 6, lane = t & 63;
    const int rb = bid >> 1, ct = bid & 1;
    const int row0 = rb * 64, col0 = ct * 64;
    const int m = lane & 15, g = lane >> 4;

    floatx4 acc[4];
#pragma unroll
    for (int cb = 0; cb < 4; ++cb) acc[cb] = (floatx4){0.f, 0.f, 0.f, 0.f};

    const int npass = DUAL ? 2 : 1;
    for (int pass = 0; pass < npass; ++pass) {
        const unsigned short* Ac = pass ? A2 : A;
        const short* Wc = (pass ? Wp2 : Wp) + ct * 8192;
        __syncthreads();
#pragma unroll
        for (int i = 0; i < 4; ++i) {   // stage W: 1024 x 16B linear
            int cbase = (i * 4 + wv) * 64;
            __builtin_amdgcn_global_load_lds(
                (const AS1 unsigned int*)(Wc + (size_t)(cbase + lane) * 8),
                (AS3 unsigned int*)(sW + cbase * 8), 16, 0, 0);
        }
#pragma unroll
        for (int i = 0; i < 4; ++i) {   // stage A: swizzled source
            int cbase = (i * 4 + wv) * 64;
            int id = cbase + lane;
            int r = id >> 4, cs = id & 15;
            int rg = row0 + r; if (rg >= NN) rg = NN - 1;
            int csrc = cs ^ (r & 7);
            __builtin_amdgcn_global_load_lds(
                (const AS1 unsigned int*)(Ac + (size_t)rg * 128 + csrc * 8),
                (AS3 unsigned int*)(sA + cbase * 8), 16, 0, 0);
        }
        asm volatile("s_waitcnt vmcnt(0)" ::: "memory");
        __builtin_amdgcn_sched_barrier(0);
        __syncthreads();

        const int r0 = wv * 16;
#pragma unroll
        for (int ks = 0; ks < 4; ++ks) {
            int cxor = (ks * 4 + g) ^ (m & 7);
            short8 af = *(const short8*)&sA[((r0 + m) * 16 + cxor) * 8];
#pragma unroll
            for (int cb = 0; cb < 4; ++cb) {
                short8 bf = *(const short8*)&sW[((cb * 4 + ks) * 64 + lane) * 8];
                acc[cb] = __builtin_amdgcn_mfma_f32_16x16x32_bf16(af, bf, acc[cb], 0, 0, 0);
            }
        }
    }

    const int rowbase = row0 + wv * 16 + g * 4;
#pragma unroll
    for (int cb = 0; cb < 4; ++cb) {
        int C = col0 + cb * 16 + m;
        float bb = NOBIAS ? 0.f : bias[C];
        if (BIAS2) bb += bias2[C];
#pragma unroll
        for (int rr = 0; rr < 4; ++rr) {
            int R = rowbase + rr;
            if (R < NN) {
                size_t idx = (size_t)R * 128 + C;
                float v = acc[cb][rr] + bb;
                if (DOELU) v = (v > 0.f) ? v : expm1f(v);
                if (OUTF32) ((float*)outv)[idx] = v;
                else        ((unsigned short*)outv)[idx] = f2bf(v);
            }
        }
    }
}

template<int DUAL, int DOELU, int OUTF32, int NOBIAS, int BIAS2>
__global__ __launch_bounds__(256)
void k_mm(const unsigned short* __restrict__ A, const unsigned short* __restrict__ A2,
          const short* __restrict__ Wp, const short* __restrict__ Wp2,
          const float* __restrict__ bias, const float* __restrict__ bias2,
          void* outv) {
    __shared__ short sMem[16384];
    gemm_body<DUAL, DOELU, OUTF32, NOBIAS, BIAS2>(blockIdx.x, A, A2, Wp, Wp2,
                                                  bias, bias2, outv, sMem, sMem + 8192);
}

// ---------------- mega1: per-bucket scatter+CSR || T1 || C1 || S1 ----------------
// scatter block b: owns bucket b's contiguous edge window; derives node degrees,
// local prefix -> row_start slice; then block-private scatter into col_idx.

__global__ __launch_bounds__(256)
void k_mega1(const int* __restrict__ bsrc, const int* __restrict__ bdst,
             const int* __restrict__ bstart, int* __restrict__ row_start,
             int* __restrict__ col_idx,
             const unsigned short* __restrict__ hB, const short* __restrict__ wpk,
             const float* __restrict__ bsk1,
             unsigned short* __restrict__ T1out, unsigned short* __restrict__ C1out,
             unsigned short* __restrict__ S1out) {
    __shared__ short sMem[16384];
    int bid = blockIdx.x;
    if (bid < NB) {
        int* lcur = (int*)sMem;          // [NPB2]
        int* sc   = lcur + NPB2;         // [512]
        int* rs   = sc + 512;            // [NPB2]
        const int t = threadIdx.x;
        const int n0 = bid * NPB2;
        const int n1 = (n0 + NPB2 < NN) ? n0 + NPB2 : NN;
        const int nn = n1 - n0;
        const int w0 = bstart[bid], w1 = bstart[bid + 1];
        for (int i = t; i < nn; i += 256) lcur[i] = 0;
        __syncthreads();
        // pass 1: local degree count
        for (int e = w0 + t; e < w1; e += 256)
            atomicAdd(&lcur[bdst[e] - n0], 1);
        __syncthreads();
        // 512-wide Hillis-Steele inclusive scan over lcur[0..nn)
        int v0 = (t < nn) ? lcur[t] : 0;
        int v1 = (t + 256 < nn) ? lcur[t + 256] : 0;
        sc[t] = v0; sc[t + 256] = v1;
        __syncthreads();
        for (int off = 1; off < 512; off <<= 1) {
            int a0 = (t >= off) ? sc[t - off] : 0;
            int a1 = (t + 256 >= off) ? sc[t + 256 - off] : 0;
            __syncthreads();
            sc[t] += a0; sc[t + 256] += a1;
            __syncthreads();
        }
        // rs = w0 + exclusive; emit row_start slice; reset cursors
        for (int i = t; i < nn; i += 256) {
            int r = w0 + sc[i] - lcur[i];
            rs[i] = r;
            row_start[n0 + i] = r;
            lcur[i] = 0;
        }
        if (bid == 0 && t == 0) row_start[NN] = NE;
        __syncthreads();
        // pass 2: scatter (block-private window)
        for (int e = w0 + t; e < w1; e += 256) {
            int d = bdst[e] - n0;
            int slot = atomicAdd(&lcur[d], 1);
            col_idx[rs[d] + slot] = bsrc[e];
        }
    } else if (bid < NB + NT) {          // T1 = hB@Wneigh1 (no bias)
        gemm_body<0, 0, 0, 1, 0>(bid - NB, hB, nullptr, wpk + 3 * 16384, nullptr,
                                 nullptr, nullptr, T1out, sMem, sMem + 8192);
    } else if (bid < NB + 2 * NT) {      // C1 = hB@Wself1 (no bias)
        gemm_body<0, 0, 0, 1, 0>(bid - NB - NT, hB, nullptr, wpk + 2 * 16384, nullptr,
                                 nullptr, nullptr, C1out, sMem, sMem + 8192);
    } else {                             // S1 = ELU(hB@Wsk1 + bsk1)
        gemm_body<0, 1, 0, 0, 0>(bid - NB - 2 * NT, hB, nullptr, wpk, nullptr,
                                 bsk1, nullptr, S1out, sMem, sMem + 8192);
    }
}

// ---------------- agg1x: X1 = ELU(C1 + mean(T1) + bc)  (fused conv1) ----------------

__global__ __launch_bounds__(256)
void k_agg1x(const unsigned short* __restrict__ T1, const int* __restrict__ row_start,
             const int* __restrict__ col_idx, const unsigned short* __restrict__ C1,
             const float* __restrict__ bc, unsigned short* __restrict__ X1out) {
    int node = (blockIdx.x * 256 + threadIdx.x) >> 6;
    int lane = threadIdx.x & 63;
    if (node >= NN) return;
    const int beg = row_start[node], end = row_start[node + 1];
    const size_t lo = (size_t)(lane * 2);
    float sx = 0.f, sy = 0.f;
    int j = beg;
#pragma unroll 1
    for (; j + 8 <= end; j += 8) {
        int s[8];
#pragma unroll
        for (int u = 0; u < 8; ++u) s[u] = col_idx[j + u];
        unsigned v[8];
#pragma unroll
        for (int u = 0; u < 8; ++u)
            v[u] = *(const unsigned*)&T1[(size_t)s[u] * 128 + lo];
#pragma unroll
        for (int u = 0; u < 8; ++u) {
            sx += bf2f((unsigned short)(v[u] & 0xffff));
            sy += bf2f((unsigned short)(v[u] >> 16));
        }
    }
#pragma unroll 1
    for (; j < end; ++j) {
        int s = col_idx[j];
        unsigned v = *(const unsigned*)&T1[(size_t)s * 128 + lo];
        sx += bf2f((unsigned short)(v & 0xffff));
        sy += bf2f((unsigned short)(v >> 16));
    }
    float inv = 1.0f / fmaxf((float)(end - beg), 1.0f);
    unsigned c = *(const unsigned*)&C1[(size_t)node * 128 + lo];
    float x = sx * inv + bf2f((unsigned short)(c & 0xffff)) + bc[lane * 2];
    float y = sy * inv + bf2f((unsigned short)(c >> 16)) + bc[lane * 2 + 1];
    x = (x > 0.f) ? x : expm1f(x);
    y = (y > 0.f) ? y : expm1f(y);
    unsigned o = (unsigned)f2bf(x) | ((unsigned)f2bf(y) << 16);
    *(unsigned*)&X1out[(size_t)node * 128 + lo] = o;
}

// ---------------- mega3: outP = X3@Wself2 + S1@Wsk2 + biases || T2 = X3@Wneigh2 ----------------

__global__ __launch_bounds__(256)
void k_mega3(const unsigned short* __restrict__ X3, const unsigned short* __restrict__ S1,
             const short* __restrict__ wpk, const float* __restrict__ bconv2,
             const float* __restrict__ bsk2, float* __restrict__ outP,
             unsigned short* __restrict__ T2out) {
    __shared__ short sMem[16384];
    int bid = blockIdx.x;
    if (bid < NT) {
        gemm_body<1, 0, 1, 0, 1>(bid, X3, S1, wpk + 6 * 16384, wpk + 1 * 16384,
                                 bconv2, bsk2, outP, sMem, sMem + 8192);
    } else {
        gemm_body<0, 0, 0, 1, 0>(bid - NT, X3, nullptr, wpk + 7 * 16384, nullptr,
                                 nullptr, nullptr, T2out, sMem, sMem + 8192);
    }
}

// ---------------- aggf: out += mean(T2)  (f32 RMW, own rows only) ----------------

__global__ __launch_bounds__(256)
void k_aggf(const unsigned short* __restrict__ T2, const int* __restrict__ row_start,
            const int* __restrict__ col_idx, float* __restrict__ out) {
    int node = (blockIdx.x * 256 + threadIdx.x) >> 6;
    int lane = threadIdx.x & 63;
    if (node >= NN) return;
    const int beg = row_start[node], end = row_start[node + 1];
    const size_t lo = (size_t)(lane * 2);
    float sx = 0.f, sy = 0.f;
    int j = beg;
#pragma unroll 1
    for (; j + 8 <= end; j += 8) {
        int s[8];
#pragma unroll
        for (int u = 0; u < 8; ++u) s[u] = col_idx[j + u];
        unsigned v[8];
#pragma unroll
        for (int u = 0; u < 8; ++u)
            v[u] = *(const unsigned*)&T2[(size_t)s[u] * 128 + lo];
#pragma unroll
        for (int u = 0; u < 8; ++u) {
            sx += bf2f((unsigned short)(v[u] & 0xffff));
            sy += bf2f((unsigned short)(v[u] >> 16));
        }
    }
#pragma unroll 1
    for (; j < end; ++j) {
        int s = col_idx[j];
        unsigned v = *(const unsigned*)&T2[(size_t)s * 128 + lo];
        sx += bf2f((unsigned short)(v & 0xffff));
        sy += bf2f((unsigned short)(v >> 16));
    }
    float inv = 1.0f / fmaxf((float)(end - beg), 1.0f);
    float2* op = (float2*)&out[(size_t)node * 128 + lo];
    float2 v = *op;
    v.x += sx * inv;
    v.y += sy * inv;
    *op = v;
}

// ---------------- launch ----------------

extern "C" void kernel_launch(void* const* d_in, const int* in_sizes, int n_in,
                              void* d_out, int out_size, void* d_ws, size_t ws_size,
                              hipStream_t stream) {
    const float* h        = (const float*)d_in[0];
    const int*   src      = (const int*)d_in[1];
    const int*   dst      = (const int*)d_in[2];
    const float* W_skip1  = (const float*)d_in[3];
    const float* b_skip1  = (const float*)d_in[4];
    const float* W_skip2  = (const float*)d_in[5];
    const float* b_skip2  = (const float*)d_in[6];
    const float* W_self1  = (const float*)d_in[7];
    const float* W_neigh1 = (const float*)d_in[8];
    const float* b_conv1  = (const float*)d_in[9];
    const float* W_si1    = (const float*)d_in[10];
    const float* b_si1    = (const float*)d_in[11];
    const float* W_si2    = (const float*)d_in[12];
    const float* b_si2    = (const float*)d_in[13];
    const float* W_self2  = (const float*)d_in[14];
    const float* W_neigh2 = (const float*)d_in[15];
    const float* b_conv2  = (const float*)d_in[16];
    float* out = (float*)d_out;

    char* ws = (char*)d_ws;
    int* bcnt      = (int*)ws;            // [128]
    int* gcur      = bcnt + 128;          // [128]
    int* bstart    = bcnt + 256;          // [129]
    int* row_start = bcnt + 100096;       // [50001] (same region as before)
    int* col_idx   = bcnt + 150272;       // [800000] -> ends at byte 3801088
    short* wpk          = (short*)(ws + 3801088);            // 8 x 16384 bf16
    unsigned short* hB  = (unsigned short*)(ws + 4063232);   // h -> X1 -> X3
    unsigned short* B1  = (unsigned short*)(ws + 16863232);  // T1 -> Y1 -> T2
    unsigned short* B2  = (unsigned short*)(ws + 29663232);  // S1
    int* bsrc           = (int*)(ws + 42463232);             // [800000]
    int* bdst           = (int*)(ws + 45663232);             // [800000]
    unsigned short* C1s = (unsigned short*)d_out;            // C1 bf16 scratch

    hipMemsetAsync(ws, 0, 128 * sizeof(int), stream);

    // cvt | bucket-count | packW
    k_prep<<<3125 + NBB + 8, 256, 0, stream>>>(h, hB, dst, bcnt,
                                               W_skip1, W_skip2, W_self1, W_neigh1,
                                               W_si1, W_si2, W_self2, W_neigh2, wpk);
    k_bscan<<<1, NB, 0, stream>>>(bcnt, gcur, bstart);

    // LDS-chunked bucketize (coalesced run writes)
    k_bucket<<<NBB, 256, 0, stream>>>(src, dst, gcur, bsrc, bdst);

    // per-bucket scatter+CSR || T1 || C1 || S1
    k_mega1<<<NB + 3 * NT, 256, 0, stream>>>(bsrc, bdst, bstart, row_start, col_idx,
                                             hB, wpk, b_skip1, B1, C1s, B2);

    // X1 = ELU(C1 + mean(T1) + bc) -> hB   (fused conv1)
    k_agg1x<<<12500, 256, 0, stream>>>(B1, row_start, col_idx, C1s, b_conv1, hB);

    // si1: Y1 = ELU(X1@Wsi1+b) -> B1
    k_mm<0, 1, 0, 0, 0><<<NT, 256, 0, stream>>>(hB, nullptr, wpk + 4 * 16384, nullptr,
                                                b_si1, nullptr, B1);
    // si2: X3 = ELU(Y1@Wsi2+b) -> hB
    k_mm<0, 1, 0, 0, 0><<<NT, 256, 0, stream>>>(B1, nullptr, wpk + 5 * 16384, nullptr,
                                                b_si2, nullptr, hB);

    // outP = X3@Wself2 + S1@Wsk2 + (bconv2+bsk2) -> f32 out || T2 = X3@Wneigh2 -> B1
    k_mega3<<<2 * NT, 256, 0, stream>>>(hB, B2, wpk, b_conv2, b_skip2, out, B1);

    // out += mean(T2)
    k_aggf<<<12500, 256, 0, stream>>>(B1, row_start, col_idx, out);
}

// Round 14
// 189.216 us; speedup vs baseline: 2.6261x; 1.0541x over previous
//
#include <hip/hip_runtime.h>
#include <math.h>

#define NN 50000
#define NE 800000
#define NRT 782          // row tiles of 64
#define NT  (NRT * 2)    // x2 col-halves = 1564 blocks per GEMM
#define NB  128          // coarse dst-buckets
#define NPB2 391         // nodes per bucket (128*391 = 50048 >= NN)
#define EPB 2048         // edges per bucketize block
#define NBB 391          // bucketize blocks (ceil(NE/EPB))

typedef __attribute__((ext_vector_type(8))) short short8;
typedef __attribute__((ext_vector_type(4))) float floatx4;

#define AS1 __attribute__((address_space(1)))
#define AS3 __attribute__((address_space(3)))

__device__ __forceinline__ unsigned short f2bf(float f) {
    unsigned u = __float_as_uint(f);
    unsigned r = (u + 0x7fff + ((u >> 16) & 1)) >> 16;
    return (unsigned short)r;
}
__device__ __forceinline__ float bf2f(unsigned short h) {
    return __uint_as_float(((unsigned)h) << 16);
}

// ---------------- prep: cvt (h->bf16) | bucket-count | packW ----------------

__global__ __launch_bounds__(256)
void k_prep(const float* __restrict__ h, unsigned short* __restrict__ hB,
            const int* __restrict__ dst, int* __restrict__ bcnt,
            const float* w0, const float* w1, const float* w2, const float* w3,
            const float* w4, const float* w5, const float* w6, const float* w7,
            short* __restrict__ wpk) {
    int bid = blockIdx.x;
    const int t = threadIdx.x;
    if (bid < 3125) {              // cvt
        int i = (bid * 256 + t) * 8;
        float4 a = *(const float4*)&h[i];
        float4 b = *(const float4*)&h[i + 4];
        short8 v;
        v[0] = (short)f2bf(a.x); v[1] = (short)f2bf(a.y);
        v[2] = (short)f2bf(a.z); v[3] = (short)f2bf(a.w);
        v[4] = (short)f2bf(b.x); v[5] = (short)f2bf(b.y);
        v[6] = (short)f2bf(b.z); v[7] = (short)f2bf(b.w);
        *(short8*)&hB[i] = v;
    } else if (bid < 3125 + NBB) { // bucket-count (LDS histogram of 128 buckets)
        __shared__ int cnt[NB];
        if (t < NB) cnt[t] = 0;
        __syncthreads();
        int base = (bid - 3125) * EPB;
#pragma unroll
        for (int i = 0; i < 8; ++i) {
            int idx = base + i * 256 + t;
            if (idx < NE) atomicAdd(&cnt[dst[idx] / NPB2], 1);
        }
        __syncthreads();
        if (t < NB && cnt[t]) atomicAdd(&bcnt[t], cnt[t]);
    } else {                       // packW, 8 blocks
        int wb = bid - 3125 - NBB;
        const float* W;
        switch (wb) {
            case 0: W = w0; break; case 1: W = w1; break;
            case 2: W = w2; break; case 3: W = w3; break;
            case 4: W = w4; break; case 5: W = w5; break;
            case 6: W = w6; break; default: W = w7; break;
        }
        short* dstp = wpk + (size_t)wb * 16384;
#pragma unroll
        for (int i = 0; i < 8; ++i) {
            int q = t + i * 256;
            int cb = q >> 8, ks = (q >> 6) & 3, lane = q & 63;
            int n = lane & 15, g = lane >> 4;
            int col = cb * 16 + n, krow = ks * 32 + g * 8;
            short8 v;
#pragma unroll
            for (int j = 0; j < 8; ++j)
                v[j] = (short)f2bf(W[(krow + j) * 128 + col]);
            *(short8*)&dstp[q * 8] = v;
        }
    }
}

// ---------------- bscan: 128-wide prefix -> gcur (cursors) + bstart ----------------

__global__ void k_bscan(const int* __restrict__ bcnt, int* __restrict__ gcur,
                        int* __restrict__ bstart) {
    __shared__ int s[NB];
    int t = threadIdx.x;
    int c = bcnt[t];
    s[t] = c;
    __syncthreads();
    for (int off = 1; off < NB; off <<= 1) {
        int v = (t >= off) ? s[t - off] : 0;
        __syncthreads();
        s[t] += v;
        __syncthreads();
    }
    int excl = s[t] - c;
    gcur[t] = excl;
    bstart[t] = excl;
    if (t == NB - 1) bstart[NB] = s[NB - 1];   // = NE
}

// ---------------- bucketize: LDS-chunked reorder into 128 dst-buckets ----------------

__global__ __launch_bounds__(256)
void k_bucket(const int* __restrict__ src, const int* __restrict__ dst,
              int* __restrict__ gcur, int* __restrict__ bsrc, int* __restrict__ bdst) {
    __shared__ int psrc[EPB];
    __shared__ int pdst[EPB];
    __shared__ int cnt[NB];
    __shared__ int ebase[NB];
    __shared__ int gbase[NB];
    const int t = threadIdx.x;
    const int e0 = blockIdx.x * EPB;
    const int M = (e0 + EPB <= NE) ? EPB : (NE - e0);

    if (t < NB) cnt[t] = 0;
    __syncthreads();

    int es[8], ed[8], rank[8];
#pragma unroll
    for (int i = 0; i < 8; ++i) {
        int idx = i * 256 + t;
        if (idx < M) {
            es[i] = src[e0 + idx];
            ed[i] = dst[e0 + idx];
            rank[i] = atomicAdd(&cnt[ed[i] / NPB2], 1);
        }
    }
    __syncthreads();
    if (t < NB) ebase[t] = cnt[t];
    __syncthreads();
    for (int off = 1; off < NB; off <<= 1) {
        int v = 0;
        if (t < NB && t >= off) v = ebase[t - off];
        __syncthreads();
        if (t < NB) ebase[t] += v;
        __syncthreads();
    }
    if (t < NB) ebase[t] -= cnt[t];   // exclusive
    __syncthreads();
#pragma unroll
    for (int i = 0; i < 8; ++i) {
        int idx = i * 256 + t;
        if (idx < M) {
            int b = ed[i] / NPB2;
            int pos = ebase[b] + rank[i];
            psrc[pos] = es[i];
            pdst[pos] = ed[i];
        }
    }
    if (t < NB && cnt[t] > 0) gbase[t] = atomicAdd(&gcur[t], cnt[t]);
    __syncthreads();
#pragma unroll
    for (int i = 0; i < 8; ++i) {
        int idx = i * 256 + t;
        if (idx < M) {
            int d = pdst[idx];
            int b = d / NPB2;
            int gpos = gbase[b] + (idx - ebase[b]);
            bsrc[gpos] = psrc[idx];
            bdst[gpos] = d;
        }
    }
}

// ---------------- GEMM body: 64x64 tile, 4 waves, wave = 16 rows ----------------

template<int DUAL, int DOELU, int OUTF32, int NOBIAS, int BIAS2>
__device__ __forceinline__ void gemm_body(
        int bid,
        const unsigned short* __restrict__ A, const unsigned short* __restrict__ A2,
        const short* __restrict__ Wp, const short* __restrict__ Wp2,
        const float* __restrict__ bias, const float* __restrict__ bias2,
        void* outv, short* sW, short* sA) {
    const int t = threadIdx.x;
    const int wv = t >> 6, lane = t & 63;
    const int rb = bid >> 1, ct = bid & 1;
    const int row0 = rb * 64, col0 = ct * 64;
    const int m = lane & 15, g = lane >> 4;

    floatx4 acc[4];
#pragma unroll
    for (int cb = 0; cb < 4; ++cb) acc[cb] = (floatx4){0.f, 0.f, 0.f, 0.f};

    const int npass = DUAL ? 2 : 1;
    for (int pass = 0; pass < npass; ++pass) {
        const unsigned short* Ac = pass ? A2 : A;
        const short* Wc = (pass ? Wp2 : Wp) + ct * 8192;
        __syncthreads();
#pragma unroll
        for (int i = 0; i < 4; ++i) {   // stage W: 1024 x 16B linear
            int cbase = (i * 4 + wv) * 64;
            __builtin_amdgcn_global_load_lds(
                (const AS1 unsigned int*)(Wc + (size_t)(cbase + lane) * 8),
                (AS3 unsigned int*)(sW + cbase * 8), 16, 0, 0);
        }
#pragma unroll
        for (int i = 0; i < 4; ++i) {   // stage A: swizzled source
            int cbase = (i * 4 + wv) * 64;
            int id = cbase + lane;
            int r = id >> 4, cs = id & 15;
            int rg = row0 + r; if (rg >= NN) rg = NN - 1;
            int csrc = cs ^ (r & 7);
            __builtin_amdgcn_global_load_lds(
                (const AS1 unsigned int*)(Ac + (size_t)rg * 128 + csrc * 8),
                (AS3 unsigned int*)(sA + cbase * 8), 16, 0, 0);
        }
        asm volatile("s_waitcnt vmcnt(0)" ::: "memory");
        __builtin_amdgcn_sched_barrier(0);
        __syncthreads();

        const int r0 = wv * 16;
#pragma unroll
        for (int ks = 0; ks < 4; ++ks) {
            int cxor = (ks * 4 + g) ^ (m & 7);
            short8 af = *(const short8*)&sA[((r0 + m) * 16 + cxor) * 8];
#pragma unroll
            for (int cb = 0; cb < 4; ++cb) {
                short8 bf = *(const short8*)&sW[((cb * 4 + ks) * 64 + lane) * 8];
                acc[cb] = __builtin_amdgcn_mfma_f32_16x16x32_bf16(af, bf, acc[cb], 0, 0, 0);
            }
        }
    }

    const int rowbase = row0 + wv * 16 + g * 4;
#pragma unroll
    for (int cb = 0; cb < 4; ++cb) {
        int C = col0 + cb * 16 + m;
        float bb = NOBIAS ? 0.f : bias[C];
        if (BIAS2) bb += bias2[C];
#pragma unroll
        for (int rr = 0; rr < 4; ++rr) {
            int R = rowbase + rr;
            if (R < NN) {
                size_t idx = (size_t)R * 128 + C;
                float v = acc[cb][rr] + bb;
                if (DOELU) v = (v > 0.f) ? v : expm1f(v);
                if (OUTF32) ((float*)outv)[idx] = v;
                else        ((unsigned short*)outv)[idx] = f2bf(v);
            }
        }
    }
}

template<int DUAL, int DOELU, int OUTF32, int NOBIAS, int BIAS2>
__global__ __launch_bounds__(256)
void k_mm(const unsigned short* __restrict__ A, const unsigned short* __restrict__ A2,
          const short* __restrict__ Wp, const short* __restrict__ Wp2,
          const float* __restrict__ bias, const float* __restrict__ bias2,
          void* outv) {
    __shared__ short sMem[16384];
    gemm_body<DUAL, DOELU, OUTF32, NOBIAS, BIAS2>(blockIdx.x, A, A2, Wp, Wp2,
                                                  bias, bias2, outv, sMem, sMem + 8192);
}

// ---------------- triple-GEMM: A staged once, 3 W-phases (T1, C1, S1) ----------------

__device__ __forceinline__ void gemm3_body(
        int bid, const unsigned short* __restrict__ A,
        const short* __restrict__ Wn, const short* __restrict__ Ws,
        const short* __restrict__ Wk, const float* __restrict__ bsk1,
        unsigned short* __restrict__ T1, unsigned short* __restrict__ C1,
        unsigned short* __restrict__ S1, short* sW, short* sA) {
    const int t = threadIdx.x;
    const int wv = t >> 6, lane = t & 63;
    const int rb = bid >> 1, ct = bid & 1;
    const int row0 = rb * 64, col0 = ct * 64;
    const int m = lane & 15, g = lane >> 4;

    // stage A once
#pragma unroll
    for (int i = 0; i < 4; ++i) {
        int cbase = (i * 4 + wv) * 64;
        int id = cbase + lane;
        int r = id >> 4, cs = id & 15;
        int rg = row0 + r; if (rg >= NN) rg = NN - 1;
        int csrc = cs ^ (r & 7);
        __builtin_amdgcn_global_load_lds(
            (const AS1 unsigned int*)(A + (size_t)rg * 128 + csrc * 8),
            (AS3 unsigned int*)(sA + cbase * 8), 16, 0, 0);
    }

#pragma unroll
    for (int ph = 0; ph < 3; ++ph) {
        if (ph) __syncthreads();   // all waves done reading sW of prev phase
        const short* Wc = (ph == 0 ? Wn : ph == 1 ? Ws : Wk) + ct * 8192;
#pragma unroll
        for (int i = 0; i < 4; ++i) {
            int cbase = (i * 4 + wv) * 64;
            __builtin_amdgcn_global_load_lds(
                (const AS1 unsigned int*)(Wc + (size_t)(cbase + lane) * 8),
                (AS3 unsigned int*)(sW + cbase * 8), 16, 0, 0);
        }
        asm volatile("s_waitcnt vmcnt(0)" ::: "memory");
        __builtin_amdgcn_sched_barrier(0);
        __syncthreads();

        floatx4 acc[4];
#pragma unroll
        for (int cb = 0; cb < 4; ++cb) acc[cb] = (floatx4){0.f, 0.f, 0.f, 0.f};
        const int r0 = wv * 16;
#pragma unroll
        for (int ks = 0; ks < 4; ++ks) {
            int cxor = (ks * 4 + g) ^ (m & 7);
            short8 af = *(const short8*)&sA[((r0 + m) * 16 + cxor) * 8];
#pragma unroll
            for (int cb = 0; cb < 4; ++cb) {
                short8 bf = *(const short8*)&sW[((cb * 4 + ks) * 64 + lane) * 8];
                acc[cb] = __builtin_amdgcn_mfma_f32_16x16x32_bf16(af, bf, acc[cb], 0, 0, 0);
            }
        }

        const int rowbase = row0 + wv * 16 + g * 4;
#pragma unroll
        for (int cb = 0; cb < 4; ++cb) {
            int C = col0 + cb * 16 + m;
            float bb = (ph == 2) ? bsk1[C] : 0.f;
#pragma unroll
            for (int rr = 0; rr < 4; ++rr) {
                int R = rowbase + rr;
                if (R < NN) {
                    size_t idx = (size_t)R * 128 + C;
                    float v = acc[cb][rr] + bb;
                    if (ph == 0)      T1[idx] = f2bf(v);
                    else if (ph == 1) C1[idx] = f2bf(v);
                    else {
                        v = (v > 0.f) ? v : expm1f(v);
                        S1[idx] = f2bf(v);
                    }
                }
            }
        }
    }
}

// ---------------- mega1: per-bucket scatter+CSR || triple-GEMM(T1,C1,S1) ----------------

__global__ __launch_bounds__(256)
void k_mega1(const int* __restrict__ bsrc, const int* __restrict__ bdst,
             const int* __restrict__ bstart, int* __restrict__ row_start,
             int* __restrict__ col_idx,
             const unsigned short* __restrict__ hB, const short* __restrict__ wpk,
             const float* __restrict__ bsk1,
             unsigned short* __restrict__ T1out, unsigned short* __restrict__ C1out,
             unsigned short* __restrict__ S1out) {
    __shared__ short sMem[16384];
    int bid = blockIdx.x;
    if (bid < NB) {
        int* lcur = (int*)sMem;          // [NPB2]
        int* sc   = lcur + NPB2;         // [512]
        int* rs   = sc + 512;            // [NPB2]
        const int t = threadIdx.x;
        const int n0 = bid * NPB2;
        const int n1 = (n0 + NPB2 < NN) ? n0 + NPB2 : NN;
        const int nn = n1 - n0;
        const int w0 = bstart[bid], w1 = bstart[bid + 1];
        for (int i = t; i < nn; i += 256) lcur[i] = 0;
        __syncthreads();
        for (int e = w0 + t; e < w1; e += 256)
            atomicAdd(&lcur[bdst[e] - n0], 1);
        __syncthreads();
        int v0 = (t < nn) ? lcur[t] : 0;
        int v1 = (t + 256 < nn) ? lcur[t + 256] : 0;
        sc[t] = v0; sc[t + 256] = v1;
        __syncthreads();
        for (int off = 1; off < 512; off <<= 1) {
            int a0 = (t >= off) ? sc[t - off] : 0;
            int a1 = (t + 256 >= off) ? sc[t + 256 - off] : 0;
            __syncthreads();
            sc[t] += a0; sc[t + 256] += a1;
            __syncthreads();
        }
        for (int i = t; i < nn; i += 256) {
            int r = w0 + sc[i] - lcur[i];
            rs[i] = r;
            row_start[n0 + i] = r;
            lcur[i] = 0;
        }
        if (bid == 0 && t == 0) row_start[NN] = NE;
        __syncthreads();
        for (int e = w0 + t; e < w1; e += 256) {
            int d = bdst[e] - n0;
            int slot = atomicAdd(&lcur[d], 1);
            col_idx[rs[d] + slot] = bsrc[e];
        }
    } else {
        gemm3_body(bid - NB, hB, wpk + 3 * 16384 /*neigh1*/, wpk + 2 * 16384 /*self1*/,
                   wpk /*skip1*/, bsk1, T1out, C1out, S1out, sMem, sMem + 8192);
    }
}

// ---------------- agg1x: X1 = ELU(C1 + mean(T1) + bc)  (2-edge-per-wave gather) ----------------

__global__ __launch_bounds__(256)
void k_agg1x(const unsigned short* __restrict__ T1, const int* __restrict__ row_start,
             const int* __restrict__ col_idx, const unsigned short* __restrict__ C1,
             const float* __restrict__ bc, unsigned short* __restrict__ X1out) {
    int node = (blockIdx.x * 256 + threadIdx.x) >> 6;
    int lane = threadIdx.x & 63;
    if (node >= NN) return;
    const int grp = lane >> 5, gl = lane & 31;
    const int beg = row_start[node], end = row_start[node + 1];
    const size_t lo = (size_t)(gl * 4);
    float a0 = 0.f, a1 = 0.f, a2 = 0.f, a3 = 0.f;
    int j = beg;
#pragma unroll 1
    for (; j + 8 <= end; j += 8) {
        int s[4];
#pragma unroll
        for (int u = 0; u < 4; ++u) s[u] = col_idx[j + 2 * u + grp];
        uint2 v[4];
#pragma unroll
        for (int u = 0; u < 4; ++u)
            v[u] = *(const uint2*)&T1[(size_t)s[u] * 128 + lo];
#pragma unroll
        for (int u = 0; u < 4; ++u) {
            a0 += bf2f((unsigned short)(v[u].x & 0xffff));
            a1 += bf2f((unsigned short)(v[u].x >> 16));
            a2 += bf2f((unsigned short)(v[u].y & 0xffff));
            a3 += bf2f((unsigned short)(v[u].y >> 16));
        }
    }
#pragma unroll 1
    for (; j < end; j += 2) {
        int e = j + grp;
        if (e < end) {
            int s = col_idx[e];
            uint2 v = *(const uint2*)&T1[(size_t)s * 128 + lo];
            a0 += bf2f((unsigned short)(v.x & 0xffff));
            a1 += bf2f((unsigned short)(v.x >> 16));
            a2 += bf2f((unsigned short)(v.y & 0xffff));
            a3 += bf2f((unsigned short)(v.y >> 16));
        }
    }
    a0 += __shfl_xor(a0, 32);
    a1 += __shfl_xor(a1, 32);
    a2 += __shfl_xor(a2, 32);
    a3 += __shfl_xor(a3, 32);
    if (lane < 32) {
        float inv = 1.0f / fmaxf((float)(end - beg), 1.0f);
        uint2 c = *(const uint2*)&C1[(size_t)node * 128 + lo];
        float4 bv = *(const float4*)&bc[lane * 4];
        float x0 = a0 * inv + bf2f((unsigned short)(c.x & 0xffff)) + bv.x;
        float x1 = a1 * inv + bf2f((unsigned short)(c.x >> 16)) + bv.y;
        float x2 = a2 * inv + bf2f((unsigned short)(c.y & 0xffff)) + bv.z;
        float x3 = a3 * inv + bf2f((unsigned short)(c.y >> 16)) + bv.w;
        x0 = (x0 > 0.f) ? x0 : expm1f(x0);
        x1 = (x1 > 0.f) ? x1 : expm1f(x1);
        x2 = (x2 > 0.f) ? x2 : expm1f(x2);
        x3 = (x3 > 0.f) ? x3 : expm1f(x3);
        uint2 o;
        o.x = (unsigned)f2bf(x0) | ((unsigned)f2bf(x1) << 16);
        o.y = (unsigned)f2bf(x2) | ((unsigned)f2bf(x3) << 16);
        *(uint2*)&X1out[(size_t)node * 128 + lo] = o;
    }
}

// ---------------- mega3: outP = X3@Wself2 + S1@Wsk2 + biases || T2 = X3@Wneigh2 ----------------

__global__ __launch_bounds__(256)
void k_mega3(const unsigned short* __restrict__ X3, const unsigned short* __restrict__ S1,
             const short* __restrict__ wpk, const float* __restrict__ bconv2,
             const float* __restrict__ bsk2, float* __restrict__ outP,
             unsigned short* __restrict__ T2out) {
    __shared__ short sMem[16384];
    int bid = blockIdx.x;
    if (bid < NT) {
        gemm_body<1, 0, 1, 0, 1>(bid, X3, S1, wpk + 6 * 16384, wpk + 1 * 16384,
                                 bconv2, bsk2, outP, sMem, sMem + 8192);
    } else {
        gemm_body<0, 0, 0, 1, 0>(bid - NT, X3, nullptr, wpk + 7 * 16384, nullptr,
                                 nullptr, nullptr, T2out, sMem, sMem + 8192);
    }
}

// ---------------- aggf: out += mean(T2)  (2-edge-per-wave gather, f32 RMW) ----------------

__global__ __launch_bounds__(256)
void k_aggf(const unsigned short* __restrict__ T2, const int* __restrict__ row_start,
            const int* __restrict__ col_idx, float* __restrict__ out) {
    int node = (blockIdx.x * 256 + threadIdx.x) >> 6;
    int lane = threadIdx.x & 63;
    if (node >= NN) return;
    const int grp = lane >> 5, gl = lane & 31;
    const int beg = row_start[node], end = row_start[node + 1];
    const size_t lo = (size_t)(gl * 4);
    float a0 = 0.f, a1 = 0.f, a2 = 0.f, a3 = 0.f;
    int j = beg;
#pragma unroll 1
    for (; j + 8 <= end; j += 8) {
        int s[4];
#pragma unroll
        for (int u = 0; u < 4; ++u) s[u] = col_idx[j + 2 * u + grp];
        uint2 v[4];
#pragma unroll
        for (int u = 0; u < 4; ++u)
            v[u] = *(const uint2*)&T2[(size_t)s[u] * 128 + lo];
#pragma unroll
        for (int u = 0; u < 4; ++u) {
            a0 += bf2f((unsigned short)(v[u].x & 0xffff));
            a1 += bf2f((unsigned short)(v[u].x >> 16));
            a2 += bf2f((unsigned short)(v[u].y & 0xffff));
            a3 += bf2f((unsigned short)(v[u].y >> 16));
        }
    }
#pragma unroll 1
    for (; j < end; j += 2) {
        int e = j + grp;
        if (e < end) {
            int s = col_idx[e];
            uint2 v = *(const uint2*)&T2[(size_t)s * 128 + lo];
            a0 += bf2f((unsigned short)(v.x & 0xffff));
            a1 += bf2f((unsigned short)(v.x >> 16));
            a2 += bf2f((unsigned short)(v.y & 0xffff));
            a3 += bf2f((unsigned short)(v.y >> 16));
        }
    }
    a0 += __shfl_xor(a0, 32);
    a1 += __shfl_xor(a1, 32);
    a2 += __shfl_xor(a2, 32);
    a3 += __shfl_xor(a3, 32);
    if (lane < 32) {
        float inv = 1.0f / fmaxf((float)(end - beg), 1.0f);
        float4* op = (float4*)&out[(size_t)node * 128 + lo];
        float4 v = *op;
        v.x += a0 * inv; v.y += a1 * inv;
        v.z += a2 * inv; v.w += a3 * inv;
        *op = v;
    }
}

// ---------------- launch ----------------

extern "C" void kernel_launch(void* const* d_in, const int* in_sizes, int n_in,
                              void* d_out, int out_size, void* d_ws, size_t ws_size,
                              hipStream_t stream) {
    const float* h        = (const float*)d_in[0];
    const int*   src      = (const int*)d_in[1];
    const int*   dst      = (const int*)d_in[2];
    const float* W_skip1  = (const float*)d_in[3];
    const float* b_skip1  = (const float*)d_in[4];
    const float* W_skip2  = (const float*)d_in[5];
    const float* b_skip2  = (const float*)d_in[6];
    const float* W_self1  = (const float*)d_in[7];
    const float* W_neigh1 = (const float*)d_in[8];
    const float* b_conv1  = (const float*)d_in[9];
    const float* W_si1    = (const float*)d_in[10];
    const float* b_si1    = (const float*)d_in[11];
    const float* W_si2    = (const float*)d_in[12];
    const float* b_si2    = (const float*)d_in[13];
    const float* W_self2  = (const float*)d_in[14];
    const float* W_neigh2 = (const float*)d_in[15];
    const float* b_conv2  = (const float*)d_in[16];
    float* out = (float*)d_out;

    char* ws = (char*)d_ws;
    int* bcnt      = (int*)ws;            // [128]
    int* gcur      = bcnt + 128;          // [128]
    int* bstart    = bcnt + 256;          // [129]
    int* row_start = bcnt + 100096;       // [50001]
    int* col_idx   = bcnt + 150272;       // [800000] -> ends at byte 3801088
    short* wpk          = (short*)(ws + 3801088);            // 8 x 16384 bf16
    unsigned short* hB  = (unsigned short*)(ws + 4063232);   // h -> X1 -> X3
    unsigned short* B1  = (unsigned short*)(ws + 16863232);  // T1 -> Y1 -> T2
    unsigned short* B2  = (unsigned short*)(ws + 29663232);  // S1
    int* bsrc           = (int*)(ws + 42463232);             // [800000]
    int* bdst           = (int*)(ws + 45663232);             // [800000]
    unsigned short* C1s = (unsigned short*)d_out;            // C1 bf16 scratch

    hipMemsetAsync(ws, 0, 128 * sizeof(int), stream);

    // cvt | bucket-count | packW
    k_prep<<<3125 + NBB + 8, 256, 0, stream>>>(h, hB, dst, bcnt,
                                               W_skip1, W_skip2, W_self1, W_neigh1,
                                               W_si1, W_si2, W_self2, W_neigh2, wpk);
    k_bscan<<<1, NB, 0, stream>>>(bcnt, gcur, bstart);

    // LDS-chunked bucketize (coalesced run writes)
    k_bucket<<<NBB, 256, 0, stream>>>(src, dst, gcur, bsrc, bdst);

    // per-bucket scatter+CSR || triple-GEMM (T1, C1, S1 share one A staging)
    k_mega1<<<NB + NT, 256, 0, stream>>>(bsrc, bdst, bstart, row_start, col_idx,
                                         hB, wpk, b_skip1, B1, C1s, B2);

    // X1 = ELU(C1 + mean(T1) + bc) -> hB   (fused conv1)
    k_agg1x<<<12500, 256, 0, stream>>>(B1, row_start, col_idx, C1s, b_conv1, hB);

    // si1: Y1 = ELU(X1@Wsi1+b) -> B1
    k_mm<0, 1, 0, 0, 0><<<NT, 256, 0, stream>>>(hB, nullptr, wpk + 4 * 16384, nullptr,
                                                b_si1, nullptr, B1);
    // si2: X3 = ELU(Y1@Wsi2+b) -> hB
    k_mm<0, 1, 0, 0, 0><<<NT, 256, 0, stream>>>(B1, nullptr, wpk + 5 * 16384, nullptr,
                                                b_si2, nullptr, hB);

    // outP = X3@Wself2 + S1@Wsk2 + (bconv2+bsk2) -> f32 out || T2 = X3@Wneigh2 -> B1
    k_mega3<<<2 * NT, 256, 0, stream>>>(hB, B2, wpk, b_conv2, b_skip2, out, B1);

    // out += mean(T2)
    k_aggf<<<12500, 256, 0, stream>>>(B1, row_start, col_idx, out);
}